// Round 7
// baseline (335.955 us; speedup 1.0000x reference)
//
#include <hip/hip_runtime.h>
#include <hip/hip_bf16.h>
#include <math.h>

#define N_DRUG 50000
#define N_DIS  20000
#define NE     250000
#define NE_PAD 250048   // 3907 full 64-row tiles (gate stored without bounds checks)

// scan geometry: segment 0 = cnt_dis (20000), segment 1 = cnt_drug (50000)
#define NB0 79     // ceil(20000/256)
#define NBT 275    // NB0 + ceil(50000/256)

typedef __bf16 bf16x8 __attribute__((ext_vector_type(8)));
typedef __bf16 bf16x4 __attribute__((ext_vector_type(4)));
typedef __bf16 bf16x2 __attribute__((ext_vector_type(2)));
typedef float  f32x4  __attribute__((ext_vector_type(4)));
typedef float  f32x2  __attribute__((ext_vector_type(2)));

__device__ __forceinline__ bf16x8 bz8() {
  bf16x8 v;
  #pragma unroll
  for (int j = 0; j < 8; ++j) v[j] = (__bf16)0.f;
  return v;
}

// Fast gelu: erf via Abramowitz-Stegun 7.1.27 (|erf err| <= 5e-4), 1/sqrt(2)
// folded into coefficients. gelu(x)=0.5*x*(2-p^-4) for x>=0, 0.5*x*p^-4 else.
__device__ __forceinline__ float gelu_fast(float x) {
  float ax = fabsf(x);
  float t = fmaf(ax, 0.019527f, 3.43654e-4f);
  t = fmaf(ax, t, 0.1151945f);
  t = fmaf(ax, t, 0.1968564f);
  float p = fmaf(ax, t, 1.0f);
  float p2 = p * p;
  float p4 = p2 * p2;
  float r = __builtin_amdgcn_rcpf(p4);
  float sel = (x >= 0.f) ? (2.0f - r) : r;
  return 0.5f * x * sel;
}

__device__ __forceinline__ float sigmoid_fast(float v) {
  return __builtin_amdgcn_rcpf(1.0f + __expf(-v));
}

// DPP row-rotate (within the 16-lane row): VALU-pipe lane exchange, no LDS.
// ctrl 0x120|N = ROW_ROR:N. Four levels (1,2,4,8) = rotation all-reduce.
template <int N>
__device__ __forceinline__ float dpp_ror(float v) {
  int r = __builtin_amdgcn_update_dpp(0, __builtin_bit_cast(int, v),
                                      0x120 | N, 0xF, 0xF, false);
  return __builtin_bit_cast(float, r);
}

// ---------------------------------------------------------------------------
// Persistent multi-segment [M,128] @ [128,128] GEMM (device body, shared by
// the standalone od launch and the fused nd∥gate launch).
// Per-segment block partition (bstart[5]); each block stages its segment's W
// to LDS ONCE, then grid-strides tiles. A-fragments load directly from global
// into registers, software-pipelined one tile ahead (no barriers in the loop).
// ---------------------------------------------------------------------------
struct Seg {
  const void* A[4];
  const float* W[4];
  const float* bias[4];
  void* out[4];
  int M[4];
  int bstart[5];
};

template <int AIN_BF16, int OUT_BF16>
__device__ __forceinline__ void gemm_seg_body(const Seg& d, int b,
                                              __bf16 (*Wt)[136])
{
  const int sidx = (b >= d.bstart[3]) ? 3 : (b >= d.bstart[2]) ? 2
                 : (b >= d.bstart[1]) ? 1 : 0;
  const int nb = d.bstart[sidx + 1] - d.bstart[sidx];
  const int lb = b - d.bstart[sidx];
  const float* W = d.W[sidx];
  const float* bias = d.bias[sidx];
  const int M = d.M[sidx];
  const int ntiles = (M + 63) >> 6;
  const int tid = threadIdx.x;
  const int wv = tid >> 6, lane = tid & 63;
  const int m16 = lane & 15, quad = lane >> 4;

  for (int idx = tid; idx < 16384; idx += 256) {
    int k = idx >> 7, n = idx & 127;
    Wt[n][k] = (__bf16)W[idx];
  }
  __syncthreads();   // the only barrier: Wt visible to all waves

  float bv[8];
  #pragma unroll
  for (int ct = 0; ct < 8; ++ct) bv[ct] = bias[ct * 16 + m16];

  auto load_afr = [&](int t, bf16x8* afr) {
    const int arow = (t << 6) + wv * 16 + m16;
    const bool ok = (t < ntiles) && (arow < M);
    if (AIN_BF16) {
      const __bf16* ap = (const __bf16*)d.A[sidx] + (long)arow * 128 + quad * 8;
      #pragma unroll
      for (int kt = 0; kt < 4; ++kt)
        afr[kt] = ok ? *(const bf16x8*)(ap + kt * 32) : bz8();
    } else {
      const float* ap = (const float*)d.A[sidx] + (long)arow * 128 + quad * 8;
      #pragma unroll
      for (int kt = 0; kt < 4; ++kt) {
        bf16x8 v = bz8();
        if (ok) {
          f32x4 lo = *(const f32x4*)(ap + kt * 32);
          f32x4 hi = *(const f32x4*)(ap + kt * 32 + 4);
          #pragma unroll
          for (int j = 0; j < 4; ++j) { v[j] = (__bf16)lo[j]; v[4 + j] = (__bf16)hi[j]; }
        }
        afr[kt] = v;
      }
    }
  };

  bf16x8 afr[4];
  if (lb < ntiles) load_afr(lb, afr);

  for (int t = lb; t < ntiles; t += nb) {
    bf16x8 nafr[4];
    load_afr(t + nb, nafr);   // in flight during this tile's MFMA + stores

    f32x4 acc[8];
    #pragma unroll
    for (int ct = 0; ct < 8; ++ct) acc[ct] = (f32x4){0.f, 0.f, 0.f, 0.f};
    #pragma unroll
    for (int kt = 0; kt < 4; ++kt) {
      #pragma unroll
      for (int ct = 0; ct < 8; ++ct) {
        bf16x8 bfr = *(const bf16x8*)&Wt[ct * 16 + m16][kt * 32 + quad * 8];
        acc[ct] = __builtin_amdgcn_mfma_f32_16x16x32_bf16(afr[kt], bfr, acc[ct], 0, 0, 0);
      }
    }

    // C/D layout: col=lane&15, row=quad*4+reg
    const int rb = (t << 6) + wv * 16 + quad * 4;
    #pragma unroll
    for (int ct = 0; ct < 8; ++ct) {
      const int col = ct * 16 + m16;
      #pragma unroll
      for (int rg = 0; rg < 4; ++rg) {
        int gr = rb + rg;
        if (gr < M) {
          float v = acc[ct][rg] + bv[ct];
          if (OUT_BF16) ((__bf16*)d.out[sidx])[(long)gr * 128 + col] = (__bf16)v;
          else          ((float*)d.out[sidx])[(long)gr * 128 + col] = v;
        }
      }
    }
    #pragma unroll
    for (int kt = 0; kt < 4; ++kt) afr[kt] = nafr[kt];
  }
}

template <int AIN_BF16, int OUT_BF16>
__global__ __launch_bounds__(256)
void gemm_seg(Seg d)
{
  __shared__ __bf16 Wt[128][136];   // W transposed: Wt[n][k]
  gemm_seg_body<AIN_BF16, OUT_BF16>(d, blockIdx.x, Wt);
}

// ---------------------------------------------------------------------------
// Edge gate device body, SORTED ORDER, EA PRE-SEEDED IN-PLACE (scatter2
// wrote each edge's bf16 ea row into the first 16 B of gate row p; layer-1
// A-frag is one sequential 16-B read of the row this wave overwrites).
// Zero-padded-K layer-1 MFMA, gelu in C-layout, wave-private LDS stripe H
// for both relayouts, coalesced b128 stores, no bounds checks on stores.
// ---------------------------------------------------------------------------
__device__ __forceinline__ void gate_body(const float* __restrict__ W2,
                                          const float* __restrict__ Wg1,
                                          const float* __restrict__ bg1,
                                          const float* __restrict__ bg2,
                                          __bf16* __restrict__ out,
                                          int gb, int gstride,
                                          __bf16 (*Wt)[136], __bf16 (*H)[136])
{
  const int tid = threadIdx.x;
  const int wv = tid >> 6, lane = tid & 63;
  const int m16 = lane & 15, quad = lane >> 4;

  for (int idx = tid; idx < 16384; idx += 256) {
    int k = idx >> 7, n = idx & 127;
    Wt[n][k] = (__bf16)W2[idx];
  }
  __syncthreads();

  // layer-1 B-fragments: B[n=ct*16+m16][k=quad*8+j] = Wg1[k][n], k<8 real
  bf16x8 b1[8];
  #pragma unroll
  for (int ct = 0; ct < 8; ++ct) {
    bf16x8 v = bz8();
    if (quad == 0) {
      #pragma unroll
      for (int j = 0; j < 8; ++j) v[j] = (__bf16)Wg1[j * 128 + ct * 16 + m16];
    }
    b1[ct] = v;
  }
  float b1v[8], b2v[8];
  #pragma unroll
  for (int ct = 0; ct < 8; ++ct) {
    b1v[ct] = bg1[ct * 16 + m16];
    b2v[ct] = bg2[ct * 16 + m16];
  }

  const int ntiles = (NE + 63) >> 6;   // 3907
  const int hr = wv * 16 + quad * 4;   // C-layout row base in H stripe
  const int ar = wv * 16 + m16;        // A-frag / row-major row in H stripe

  for (int t = gb; t < ntiles; t += gstride) {
    const int p = (t << 6) + wv * 16 + m16;   // sorted position == out row

    // layer-1 A-frag: quad 0 reads the pre-seeded bf16 ea row (sequential
    // 16 B; pad rows zero-seeded by scatter2), other quads zero.
    bf16x8 a1 = bz8();
    if (quad == 0)
      a1 = *(const bf16x8*)(out + (long)p * 128);

    f32x4 h[8];
    #pragma unroll
    for (int ct = 0; ct < 8; ++ct)
      h[ct] = __builtin_amdgcn_mfma_f32_16x16x32_bf16(a1, b1[ct], (f32x4){0.f,0.f,0.f,0.f}, 0, 0, 0);

    // bias + gelu in C-layout -> wave-private H stripe (in-order DS pipe)
    #pragma unroll
    for (int ct = 0; ct < 8; ++ct) {
      const int col = ct * 16 + m16;
      #pragma unroll
      for (int rg = 0; rg < 4; ++rg)
        H[hr + rg][col] = (__bf16)gelu_fast(h[ct][rg] + b1v[ct]);
    }
    asm volatile("s_waitcnt lgkmcnt(0)" ::: "memory");

    bf16x8 afr[4];
    #pragma unroll
    for (int kt = 0; kt < 4; ++kt)
      afr[kt] = *(const bf16x8*)&H[ar][kt * 32 + quad * 8];
    asm volatile("" ::: "memory");

    f32x4 acc[8];
    #pragma unroll
    for (int ct = 0; ct < 8; ++ct) acc[ct] = (f32x4){0.f, 0.f, 0.f, 0.f};
    #pragma unroll
    for (int kt = 0; kt < 4; ++kt) {
      #pragma unroll
      for (int ct = 0; ct < 8; ++ct) {
        bf16x8 bfr = *(const bf16x8*)&Wt[ct * 16 + m16][kt * 32 + quad * 8];
        acc[ct] = __builtin_amdgcn_mfma_f32_16x16x32_bf16(afr[kt], bfr, acc[ct], 0, 0, 0);
      }
    }

    // sigmoid in C-layout -> H stripe again (safe: in-order per-wave DS)
    #pragma unroll
    for (int ct = 0; ct < 8; ++ct) {
      const int col = ct * 16 + m16;
      #pragma unroll
      for (int rg = 0; rg < 4; ++rg)
        H[hr + rg][col] = (__bf16)sigmoid_fast(acc[ct][rg] + b2v[ct]);
    }
    asm volatile("s_waitcnt lgkmcnt(0)" ::: "memory");

    bf16x8 gout[4];
    #pragma unroll
    for (int kt = 0; kt < 4; ++kt)
      gout[kt] = *(const bf16x8*)&H[ar][kt * 32 + quad * 8];
    asm volatile("" ::: "memory");

    __bf16* op = out + (long)p * 128 + quad * 8;
    #pragma unroll
    for (int kt = 0; kt < 4; ++kt)
      *(bf16x8*)(op + kt * 32) = gout[kt];
  }
}

// ---------------------------------------------------------------------------
// FUSED nd-GEMM ∥ gate: the two kernels are mutually independent (gate needs
// only scatter2's seeds; nd-GEMM needs only inputs+weights) and have
// complementary profiles (HBM+MFMA vs VALU+DS). Even blocks run gate, odd
// blocks run the 4-segment node-transform GEMM; the 52 KB LDS arena is
// branch-local (Wt for both; gate additionally carves H above gemm's Wt).
// 1536 blocks at 52 KB -> 3 blocks/CU resident, mixed per CU.
// ---------------------------------------------------------------------------
__global__ __launch_bounds__(256, 3)
void fused_nd_gate(Seg d,
                   const float* __restrict__ W2, const float* __restrict__ Wg1,
                   const float* __restrict__ bg1, const float* __restrict__ bg2,
                   __bf16* __restrict__ gate_out)
{
  __shared__ __align__(16) char smem[52224];
  __bf16 (*Wt)[136] = (__bf16 (*)[136])smem;            // 128*136*2 = 34816 B
  __bf16 (*H)[136]  = (__bf16 (*)[136])(smem + 34816);  //  64*136*2 = 17408 B

  const int vb = blockIdx.x >> 1;   // virtual block id within each half
  if (blockIdx.x & 1) {
    gemm_seg_body<0, 1>(d, vb, Wt);
  } else {
    gate_body(W2, Wg1, bg1, bg2, gate_out, vb, 768, Wt, H);
  }
}

// ---------------------------------------------------------------------------
// Counting sort of edges by destination node (both edge types per launch).
// scatter2 materializes ssrc[p] = si[sorted[p]] AND seeds gate row p with
// the bf16-converted ea row of edge i (coalesced EA read since i is linear;
// scattered 16-B write). Block 0 zero-seeds the 48 pad rows.
// ---------------------------------------------------------------------------
__global__ __launch_bounds__(256)
void histo2(const int* __restrict__ di_t, const int* __restrict__ di_r,
            int* __restrict__ cnt_dis, int* __restrict__ cnt_drug, int half) {
  int b = blockIdx.x;
  if (b < half) {
    int i = b * 256 + threadIdx.x;
    if (i < NE) atomicAdd(&cnt_dis[di_t[i]], 1);
  } else {
    int i = (b - half) * 256 + threadIdx.x;
    if (i < NE) atomicAdd(&cnt_drug[di_r[i]], 1);
  }
}

__global__ __launch_bounds__(256)
void scatter2(const int* __restrict__ di_t, const int* __restrict__ di_r,
              const int* __restrict__ si_t, const int* __restrict__ si_r,
              const float* __restrict__ EA,
              int* __restrict__ cur_dis, int* __restrict__ cur_drug,
              int* __restrict__ ssrc_t, int* __restrict__ ssrc_r,
              __bf16* __restrict__ gate_ea, int half) {
  int b = blockIdx.x;
  if (b < half) {
    int i = b * 256 + threadIdx.x;
    if (i < NE) {
      int p = atomicAdd(&cur_dis[di_t[i]], 1);
      ssrc_t[p] = si_t[i];
      // coalesced EA read (i linear), bf16 convert, seed gate row p
      f32x4 e0 = *(const f32x4*)(EA + (long)i * 8);
      f32x4 e1 = *(const f32x4*)(EA + (long)i * 8 + 4);
      bf16x8 v;
      #pragma unroll
      for (int j = 0; j < 4; ++j) { v[j] = (__bf16)e0[j]; v[4 + j] = (__bf16)e1[j]; }
      *(bf16x8*)(gate_ea + (long)p * 128) = v;
    }
    if (b == 0 && threadIdx.x < NE_PAD - NE) {
      // zero-seed pad rows' a1 slots (keeps pad gate outputs finite)
      *(bf16x8*)(gate_ea + (long)(NE + threadIdx.x) * 128) = bz8();
    }
  } else {
    int i = (b - half) * 256 + threadIdx.x;
    if (i < NE) {
      int p = atomicAdd(&cur_drug[di_r[i]], 1);
      ssrc_r[p] = si_r[i];
    }
  }
}

// ---------------------------------------------------------------------------
// Device-wide segmented exclusive scan over concatenated cnt_dis||cnt_drug.
// ---------------------------------------------------------------------------
__device__ __forceinline__ void seg_geom(int b, int& base, int& n, int& lb) {
  if (b < NB0) { base = 0;     n = 20000; lb = b; }
  else         { base = 20000; n = 50000; lb = b - NB0; }
}

__global__ __launch_bounds__(256)
void scan_partial(const int* __restrict__ cnt, int* __restrict__ bsum) {
  __shared__ int sh[256];
  int b = blockIdx.x, t = threadIdx.x;
  int base, n, lb; seg_geom(b, base, n, lb);
  int i = lb * 256 + t;
  sh[t] = (i < n) ? cnt[base + i] : 0;
  __syncthreads();
  for (int d = 1; d < 256; d <<= 1) {
    int vv = (t >= d) ? sh[t - d] : 0;
    __syncthreads();
    sh[t] += vv;
    __syncthreads();
  }
  if (t == 255) bsum[b] = sh[255];
}

__global__ __launch_bounds__(512)
void scan_block(const int* __restrict__ bsum, int* __restrict__ bexc) {
  __shared__ int v[512];
  __shared__ int f[512];
  int t = threadIdx.x;
  int own = (t < NBT) ? bsum[t] : 0;
  v[t] = own;
  f[t] = (t == 0 || t == NB0 || t >= NBT) ? 1 : 0;
  __syncthreads();
  for (int d = 1; d < 512; d <<= 1) {
    int vv = 0, ff = 1;
    if (t >= d) { vv = v[t - d]; ff = f[t - d]; }
    __syncthreads();
    if (t >= d && !f[t]) { v[t] += vv; f[t] |= ff; }
    __syncthreads();
  }
  if (t < NBT) bexc[t] = v[t] - own;   // exclusive within segment
}

__global__ __launch_bounds__(256)
void scan_final(const int* __restrict__ cnt, const int* __restrict__ bexc,
                int* __restrict__ offs, int* __restrict__ cursor) {
  __shared__ int sh[256];
  int b = blockIdx.x, t = threadIdx.x;
  int base, n, lb; seg_geom(b, base, n, lb);
  int i = lb * 256 + t;
  int own = (i < n) ? cnt[base + i] : 0;
  sh[t] = own;
  __syncthreads();
  for (int d = 1; d < 256; d <<= 1) {
    int vv = (t >= d) ? sh[t - d] : 0;
    __syncthreads();
    sh[t] += vv;
    __syncthreads();
  }
  int off = bexc[b] + sh[t] - own;
  if (i < n) { offs[base + i] = off; cursor[base + i] = off; }
}

// ---------------------------------------------------------------------------
// Merged gather-side aggregation, SCALARIZED control/address plane.
// One 64-lane wave per destination node; lane owns channels {2l, 2l+1}.
//  * batch-level WAVE-UNIFORM guards (m SGPR -> s_cbranch): no loads issued
//    past the last needed batch.
//  * 3-stage row pipeline: ids 3 batches ahead (SGPRs), rows in flight for
//    batches j+4 and j+8 while batch j computes.
//  * scalar clamps, DPP row_ror reduce, log2-domain exp, masked ex.
// ---------------------------------------------------------------------------
__global__ __launch_bounds__(256)
void aggregate2(const __bf16* __restrict__ Xs_t, const __bf16* __restrict__ Xd_t,
                const __bf16* __restrict__ Xs_r, const __bf16* __restrict__ Xd_r,
                const int* __restrict__ ssrc_t, const int* __restrict__ ssrc_r,
                const int* __restrict__ offs, const int* __restrict__ cnt,
                const __bf16* __restrict__ gate_s,
                const float* __restrict__ attn_t, const float* __restrict__ attn_r,
                __bf16* __restrict__ aggr_dis, __bf16* __restrict__ aggr_drug)
{
  const int gw0 = (int)((blockIdx.x * 256 + threadIdx.x) >> 6);
  if (gw0 >= N_DIS + N_DRUG) return;
  const int gw = __builtin_amdgcn_readfirstlane(gw0);   // wave-uniform -> SGPR
  const int lane = threadIdx.x & 63;
  const int c = lane * 2;
  const bool isDis = gw < N_DIS;
  const int node = isDis ? gw : gw - N_DIS;
  const __bf16* __restrict__ Xs = isDis ? Xs_t : Xs_r;
  const __bf16* __restrict__ Xd = isDis ? Xd_t : Xd_r;
  const int* __restrict__ ssrc = isDis ? ssrc_t : ssrc_r;
  const float* __restrict__ attn = isDis ? attn_t : attn_r;
  __bf16* __restrict__ outp = isDis ? aggr_dis : aggr_drug;
  const int Ns = isDis ? N_DRUG : N_DIS;

  const int start = __builtin_amdgcn_readfirstlane(offs[gw]);
  const int m     = __builtin_amdgcn_readfirstlane(cnt[gw]);

  // per-lane constants; 1/sqrt(HD) and log2(e) folded into the logit terms
  const float LOG2E = 1.4426950408889634f;
  f32x2 at = *(const f32x2*)(attn + c);
  bf16x2 xdb = *(const bf16x2*)(Xd + (size_t)node * 128 + c);
  const float xd0 = (float)xdb[0], xd1 = (float)xdb[1];
  const float xdl0 = xd0 * (0.17677669529663687f * LOG2E);
  const float xdl1 = xd1 * (0.17677669529663687f * LOG2E);
  const float at0 = at[0] * LOG2E, at1 = at[1] * LOG2E;

  // scalar source-id fetch: clamped index, value forced to SGPR, clamped to
  // a valid row so the gather address is always in initialized memory.
  auto sfetch = [&](int jn) -> int {
    int idx = start + jn;
    if (idx > NE - 1) idx = NE - 1;                     // scalar clamp
    int s = __builtin_amdgcn_readfirstlane(ssrc[idx]);
    return ((unsigned)s < (unsigned)Ns) ? s : 0;        // scalar clamp
  };
  auto row_load = [&](int s) -> bf16x2 {                // SGPR base + lane voff
    return *(const bf16x2*)(Xs + (size_t)s * 128 + c);
  };
  auto gate_load = [&](int jn) -> bf16x2 {              // sequential rows
    return *(const bf16x2*)(gate_s + (size_t)(start + jn) * 128 + c);
  };

  const bf16x2 z2 = {(__bf16)0.f, (__bf16)0.f};
  bf16x2 xa[4], ga[4], xb[4], gb[4];
  #pragma unroll
  for (int u = 0; u < 4; ++u) { xa[u] = z2; ga[u] = z2; xb[u] = z2; gb[u] = z2; }

  // ids for batches 0/1/2 — independent scalar loads, one lgkm wait covers all
  int s0[4], s1[4], s2[4];
  #pragma unroll
  for (int u = 0; u < 4; ++u) s0[u] = sfetch(u);
  #pragma unroll
  for (int u = 0; u < 4; ++u) s1[u] = sfetch(4 + u);
  #pragma unroll
  for (int u = 0; u < 4; ++u) s2[u] = sfetch(8 + u);

  // rows for batch 0 (always) and batch 1 (if it exists)
  #pragma unroll
  for (int u = 0; u < 4; ++u) {
    xa[u] = row_load(s0[u]);
    if (isDis) ga[u] = gate_load(u);
  }
  if (m > 4) {
    #pragma unroll
    for (int u = 0; u < 4; ++u) {
      xb[u] = row_load(s1[u]);
      if (isDis) gb[u] = gate_load(4 + u);
    }
  }

  float n0 = 0.f, n1 = 0.f, den = 0.f;

  for (int j = 0; j < m; j += 4) {
    // issue rows for batch j+8 (ids already in SGPRs); refill ids for j+12.
    // all guards wave-uniform (m, j scalar) -> no divergence, no waste.
    bf16x2 xc[4], gc[4];
    #pragma unroll
    for (int u = 0; u < 4; ++u) { xc[u] = z2; gc[u] = z2; }
    if (j + 8 < m) {
      #pragma unroll
      for (int u = 0; u < 4; ++u) {
        xc[u] = row_load(s2[u]);
        if (isDis) gc[u] = gate_load(j + 8 + u);
      }
    }
    if (j + 12 < m) {
      #pragma unroll
      for (int u = 0; u < 4; ++u) s2[u] = sfetch(j + 12 + u);
    }

    // compute batch j (4 edges, 2 channels/lane)
    float part[4], mm0[4], mm1[4];
    #pragma unroll
    for (int u = 0; u < 4; ++u) {
      float xs0 = (float)xa[u][0], xs1 = (float)xa[u][1];
      float m0 = xs0 + xd0, m1 = xs1 + xd1;
      if (isDis) { m0 *= (float)ga[u][0]; m1 *= (float)ga[u][1]; }
      mm0[u] = m0; mm1[u] = m1;
      part[u] = xs0 * xdl0 + xs1 * xdl1 + m0 * at0 + m1 * at1;  // log2 domain
    }
    // per-head (16-lane row) rotation all-reduce, 4 interleaved VALU chains
    #pragma unroll
    for (int u = 0; u < 4; ++u) part[u] += dpp_ror<1>(part[u]);
    #pragma unroll
    for (int u = 0; u < 4; ++u) part[u] += dpp_ror<2>(part[u]);
    #pragma unroll
    for (int u = 0; u < 4; ++u) part[u] += dpp_ror<4>(part[u]);
    #pragma unroll
    for (int u = 0; u < 4; ++u) part[u] += dpp_ror<8>(part[u]);

    #pragma unroll
    for (int u = 0; u < 4; ++u) {
      float ex = (j + u < m) ? __builtin_amdgcn_exp2f(part[u]) : 0.f;
      n0 += mm0[u] * ex;
      n1 += mm1[u] * ex;
      den += ex;
    }
    // rotate the 3-stage row pipeline
    #pragma unroll
    for (int u = 0; u < 4; ++u) {
      xa[u] = xb[u]; ga[u] = gb[u];
      xb[u] = xc[u]; gb[u] = gc[u];
    }
  }

  float r = __builtin_amdgcn_rcpf(den + 1e-16f);
  bf16x2 o;
  o[0] = (__bf16)(n0 * r);
  o[1] = (__bf16)(n1 * r);
  *(bf16x2*)(outp + (size_t)node * 128 + c) = o;
}

// ---------------------------------------------------------------------------
extern "C" void kernel_launch(void* const* d_in, const int* in_sizes, int n_in,
                              void* d_out, int out_size, void* d_ws, size_t ws_size,
                              hipStream_t stream)
{
  const float* x_drug  = (const float*)d_in[0];
  const float* x_dis   = (const float*)d_in[1];
  const float* ea      = (const float*)d_in[2];
  const int*   si_t    = (const int*)d_in[3];
  const int*   di_t    = (const int*)d_in[4];
  const int*   si_r    = (const int*)d_in[5];
  const int*   di_r    = (const int*)d_in[6];
  const float* Ws_t    = (const float*)d_in[7];
  const float* bs_t    = (const float*)d_in[8];
  const float* Wd_t    = (const float*)d_in[9];
  const float* bd_t    = (const float*)d_in[10];
  const float* attn_t  = (const float*)d_in[11];
  const float* Wg1     = (const float*)d_in[12];
  const float* bg1     = (const float*)d_in[13];
  const float* Wg2     = (const float*)d_in[14];
  const float* bg2     = (const float*)d_in[15];
  const float* Ws_r    = (const float*)d_in[16];
  const float* bs_r    = (const float*)d_in[17];
  const float* Wd_r    = (const float*)d_in[18];
  const float* bd_r    = (const float*)d_in[19];
  const float* attn_r  = (const float*)d_in[20];
  const float* Wo_drug = (const float*)d_in[21];
  const float* bo_drug = (const float*)d_in[22];
  const float* Wo_dis  = (const float*)d_in[23];
  const float* bo_dis  = (const float*)d_in[24];

  // workspace layout (~104 MB); X/gate tensors bf16.
  // aggr_dis aliases Xd_t, aggr_drug aliases Xd_r (row-for-row safe).
  __bf16* wsb      = (__bf16*)d_ws;
  __bf16* Xs_t     = wsb;                  // 50000*128
  __bf16* Xd_t     = Xs_t + 6400000;       // 20000*128 (-> aggr_dis)
  __bf16* Xs_r     = Xd_t + 2560000;       // 20000*128
  __bf16* Xd_r     = Xs_r + 2560000;       // 50000*128 (-> aggr_drug)
  __bf16* gate     = Xd_r + 6400000;       // NE_PAD*128, SORTED order; rows
                                           // pre-seeded with bf16 ea (16 B)
  int* cnt_dis    = (int*)(gate + (long)NE_PAD * 128);  // 20000  --+ contiguous:
  int* cnt_drug   = cnt_dis + 20000;       // 50000             | zeroed+scanned
  int* offs_dis   = cnt_drug + 50000;      // 20000             | as one region
  int* offs_drug  = offs_dis + 20000;      // 50000             |
  int* cur_dis    = offs_drug + 50000;     // 20000             |
  int* cur_drug   = cur_dis + 20000;       // 50000           --+
  int* sorted_t   = cur_drug + 50000;      // 250000 (UNUSED now; slot kept)
  int* ssrc_t     = sorted_t + 250000;     // 250000
  int* ssrc_r     = ssrc_t + 250000;       // 250000
  int* bsum       = ssrc_r + 250000;       // 275
  int* bexc       = bsum + 512;            // 275

  __bf16* aggr_dis  = Xd_t;
  __bf16* aggr_drug = Xd_r;

  float* out_drug = (float*)d_out;
  float* out_dis  = out_drug + (long)N_DRUG * 128;

  hipMemsetAsync(cnt_dis, 0, 70000 * sizeof(int), stream);

  const int eb = (NE + 255) / 256;         // 977

  // counting sort by destination (both convs), device-wide 3-phase scan
  histo2<<<2 * eb, 256, 0, stream>>>(di_t, di_r, cnt_dis, cnt_drug, eb);
  scan_partial<<<NBT, 256, 0, stream>>>(cnt_dis, bsum);
  scan_block<<<1, 512, 0, stream>>>(bsum, bexc);
  scan_final<<<NBT, 256, 0, stream>>>(cnt_dis, bexc, offs_dis, cur_dis);
  scatter2<<<2 * eb, 256, 0, stream>>>(di_t, di_r, si_t, si_r, ea,
                                       cur_dis, cur_drug, ssrc_t, ssrc_r,
                                       gate, eb);

  // FUSED: 4 node-transform GEMMs (odd blocks) ∥ edge gate (even blocks).
  // Independent work, complementary pipes; 1536 blocks at 52 KB -> 3/CU.
  Seg nd;
  nd.A[0] = x_drug; nd.W[0] = Ws_t; nd.bias[0] = bs_t; nd.out[0] = Xs_t; nd.M[0] = N_DRUG;
  nd.A[1] = x_dis;  nd.W[1] = Wd_t; nd.bias[1] = bd_t; nd.out[1] = Xd_t; nd.M[1] = N_DIS;
  nd.A[2] = x_dis;  nd.W[2] = Ws_r; nd.bias[2] = bs_r; nd.out[2] = Xs_r; nd.M[2] = N_DIS;
  nd.A[3] = x_drug; nd.W[3] = Wd_r; nd.bias[3] = bd_r; nd.out[3] = Xd_r; nd.M[3] = N_DRUG;
  nd.bstart[0] = 0; nd.bstart[1] = 274; nd.bstart[2] = 384; nd.bstart[3] = 494; nd.bstart[4] = 768;
  fused_nd_gate<<<1536, 256, 0, stream>>>(nd, Wg2, Wg1, bg1, bg2, gate);

  // merged gather-side aggregation: 70000 waves, one per destination node
  aggregate2<<<(N_DIS + N_DRUG + 3) / 4, 256, 0, stream>>>(
      Xs_t, Xd_t, Xs_r, Xd_r, ssrc_t, ssrc_r, offs_dis, cnt_dis,
      gate, attn_t, attn_r, aggr_dis, aggr_drug);

  // 2 output linears, persistent per-segment blocks (tiles 782/313)
  Seg od;
  od.A[0] = aggr_drug; od.W[0] = Wo_drug; od.bias[0] = bo_drug; od.out[0] = out_drug; od.M[0] = N_DRUG;
  od.A[1] = aggr_dis;  od.W[1] = Wo_dis;  od.bias[1] = bo_dis;  od.out[1] = out_dis;  od.M[1] = N_DIS;
  od.A[2] = od.A[1];   od.W[2] = od.W[1]; od.bias[2] = od.bias[1]; od.out[2] = od.out[1]; od.M[2] = N_DIS;
  od.A[3] = od.A[1];   od.W[3] = od.W[1]; od.bias[3] = od.bias[1]; od.out[3] = od.out[1]; od.M[3] = N_DIS;
  od.bstart[0] = 0; od.bstart[1] = 548; od.bstart[2] = 768; od.bstart[3] = 768; od.bstart[4] = 768;
  gemm_seg<1, 0><<<768, 256, 0, stream>>>(od);
}

// Round 8
// 324.945 us; speedup vs baseline: 1.0339x; 1.0339x over previous
//
#include <hip/hip_runtime.h>
#include <hip/hip_bf16.h>
#include <math.h>

#define N_DRUG 50000
#define N_DIS  20000
#define NE     250000
#define NE_PAD 250048   // 3907 full 64-row tiles (gate stored without bounds checks)

// scan geometry: segment 0 = cnt_dis (20000), segment 1 = cnt_drug (50000)
#define NB0 79     // ceil(20000/256)
#define NBT 275    // NB0 + ceil(50000/256)

typedef __bf16 bf16x8 __attribute__((ext_vector_type(8)));
typedef __bf16 bf16x4 __attribute__((ext_vector_type(4)));
typedef __bf16 bf16x2 __attribute__((ext_vector_type(2)));
typedef float  f32x4  __attribute__((ext_vector_type(4)));
typedef float  f32x2  __attribute__((ext_vector_type(2)));

__device__ __forceinline__ bf16x8 bz8() {
  bf16x8 v;
  #pragma unroll
  for (int j = 0; j < 8; ++j) v[j] = (__bf16)0.f;
  return v;
}

// Fast gelu: erf via Abramowitz-Stegun 7.1.27 (|erf err| <= 5e-4), 1/sqrt(2)
// folded into coefficients. gelu(x)=0.5*x*(2-p^-4) for x>=0, 0.5*x*p^-4 else.
__device__ __forceinline__ float gelu_fast(float x) {
  float ax = fabsf(x);
  float t = fmaf(ax, 0.019527f, 3.43654e-4f);
  t = fmaf(ax, t, 0.1151945f);
  t = fmaf(ax, t, 0.1968564f);
  float p = fmaf(ax, t, 1.0f);
  float p2 = p * p;
  float p4 = p2 * p2;
  float r = __builtin_amdgcn_rcpf(p4);
  float sel = (x >= 0.f) ? (2.0f - r) : r;
  return 0.5f * x * sel;
}

__device__ __forceinline__ float sigmoid_fast(float v) {
  return __builtin_amdgcn_rcpf(1.0f + __expf(-v));
}

// DPP row-rotate (within the 16-lane row): VALU-pipe lane exchange, no LDS.
// ctrl 0x120|N = ROW_ROR:N. Four levels (1,2,4,8) = rotation all-reduce.
template <int N>
__device__ __forceinline__ float dpp_ror(float v) {
  int r = __builtin_amdgcn_update_dpp(0, __builtin_bit_cast(int, v),
                                      0x120 | N, 0xF, 0xF, false);
  return __builtin_bit_cast(float, r);
}

// ---------------------------------------------------------------------------
// Persistent multi-segment [M,128] @ [128,128] GEMM.
// Per-segment block partition (bstart[5]); each block stages its segment's W
// to LDS ONCE, then grid-strides tiles. A-fragments load directly from global
// into registers, software-pipelined one tile ahead (no barriers in the loop).
// ---------------------------------------------------------------------------
struct Seg {
  const void* A[4];
  const float* W[4];
  const float* bias[4];
  void* out[4];
  int M[4];
  int bstart[5];
};

template <int AIN_BF16, int OUT_BF16>
__global__ __launch_bounds__(256)
void gemm_seg(Seg d)
{
  __shared__ __bf16 Wt[128][136];   // W transposed: Wt[n][k]

  const int b = blockIdx.x;
  const int sidx = (b >= d.bstart[3]) ? 3 : (b >= d.bstart[2]) ? 2
                 : (b >= d.bstart[1]) ? 1 : 0;
  const int nb = d.bstart[sidx + 1] - d.bstart[sidx];
  const int lb = b - d.bstart[sidx];
  const float* W = d.W[sidx];
  const float* bias = d.bias[sidx];
  const int M = d.M[sidx];
  const int ntiles = (M + 63) >> 6;
  const int tid = threadIdx.x;
  const int wv = tid >> 6, lane = tid & 63;
  const int m16 = lane & 15, quad = lane >> 4;

  for (int idx = tid; idx < 16384; idx += 256) {
    int k = idx >> 7, n = idx & 127;
    Wt[n][k] = (__bf16)W[idx];
  }
  __syncthreads();   // the only barrier: Wt visible to all waves

  float bv[8];
  #pragma unroll
  for (int ct = 0; ct < 8; ++ct) bv[ct] = bias[ct * 16 + m16];

  auto load_afr = [&](int t, bf16x8* afr) {
    const int arow = (t << 6) + wv * 16 + m16;
    const bool ok = (t < ntiles) && (arow < M);
    if (AIN_BF16) {
      const __bf16* ap = (const __bf16*)d.A[sidx] + (long)arow * 128 + quad * 8;
      #pragma unroll
      for (int kt = 0; kt < 4; ++kt)
        afr[kt] = ok ? *(const bf16x8*)(ap + kt * 32) : bz8();
    } else {
      const float* ap = (const float*)d.A[sidx] + (long)arow * 128 + quad * 8;
      #pragma unroll
      for (int kt = 0; kt < 4; ++kt) {
        bf16x8 v = bz8();
        if (ok) {
          f32x4 lo = *(const f32x4*)(ap + kt * 32);
          f32x4 hi = *(const f32x4*)(ap + kt * 32 + 4);
          #pragma unroll
          for (int j = 0; j < 4; ++j) { v[j] = (__bf16)lo[j]; v[4 + j] = (__bf16)hi[j]; }
        }
        afr[kt] = v;
      }
    }
  };

  bf16x8 afr[4];
  if (lb < ntiles) load_afr(lb, afr);

  for (int t = lb; t < ntiles; t += nb) {
    bf16x8 nafr[4];
    load_afr(t + nb, nafr);   // in flight during this tile's MFMA + stores

    f32x4 acc[8];
    #pragma unroll
    for (int ct = 0; ct < 8; ++ct) acc[ct] = (f32x4){0.f, 0.f, 0.f, 0.f};
    #pragma unroll
    for (int kt = 0; kt < 4; ++kt) {
      #pragma unroll
      for (int ct = 0; ct < 8; ++ct) {
        bf16x8 bfr = *(const bf16x8*)&Wt[ct * 16 + m16][kt * 32 + quad * 8];
        acc[ct] = __builtin_amdgcn_mfma_f32_16x16x32_bf16(afr[kt], bfr, acc[ct], 0, 0, 0);
      }
    }

    // C/D layout: col=lane&15, row=quad*4+reg
    const int rb = (t << 6) + wv * 16 + quad * 4;
    #pragma unroll
    for (int ct = 0; ct < 8; ++ct) {
      const int col = ct * 16 + m16;
      #pragma unroll
      for (int rg = 0; rg < 4; ++rg) {
        int gr = rb + rg;
        if (gr < M) {
          float v = acc[ct][rg] + bv[ct];
          if (OUT_BF16) ((__bf16*)d.out[sidx])[(long)gr * 128 + col] = (__bf16)v;
          else          ((float*)d.out[sidx])[(long)gr * 128 + col] = v;
        }
      }
    }
    #pragma unroll
    for (int kt = 0; kt < 4; ++kt) afr[kt] = nafr[kt];
  }
}

// ---------------------------------------------------------------------------
// Edge gate, SORTED ORDER: row p of `out` is the gate of edge sorted_t[p],
// so the aggregate reads it fully sequentially. ea rows gathered (32 B,
// hidden under MFMA + TLP). 768 blocks (3 blocks/CU at 52 KB LDS ->
// 12 waves/CU).
//
// R8 (vs R5-green): the SECOND LDS round-trip (sigmoid -> H -> b128 reads
// -> global) is replaced by direct C-layout global stores. Each store
// instruction covers 4x32-B segments (m16 -> 16 contiguous cols, quad ->
// 4 rows); L2 write-combines, WRITE_SIZE unchanged. Removes ~36 DS ops +
// one lgkmcnt(0) drain per tile-wave and ~half the bank conflicts. The
// gelu LDS trip stays (genuinely needed for layer-2 A-frag relayout).
// ---------------------------------------------------------------------------
__global__ __launch_bounds__(256)
void gate_kernel(const float* __restrict__ EA, const float* __restrict__ W2,
                 const float* __restrict__ Wg1, const float* __restrict__ bg1,
                 const float* __restrict__ bg2, const int* __restrict__ sorted_t,
                 __bf16* __restrict__ out)
{
  __shared__ __bf16 Wt[128][136];
  __shared__ __bf16 H[64][136];
  const int tid = threadIdx.x;
  const int wv = tid >> 6, lane = tid & 63;
  const int m16 = lane & 15, quad = lane >> 4;

  for (int idx = tid; idx < 16384; idx += 256) {
    int k = idx >> 7, n = idx & 127;
    Wt[n][k] = (__bf16)W2[idx];
  }
  __syncthreads();

  // layer-1 B-fragments: B[n=ct*16+m16][k=quad*8+j] = Wg1[k][n], k<8 real
  bf16x8 b1[8];
  #pragma unroll
  for (int ct = 0; ct < 8; ++ct) {
    bf16x8 v = bz8();
    if (quad == 0) {
      #pragma unroll
      for (int j = 0; j < 8; ++j) v[j] = (__bf16)Wg1[j * 128 + ct * 16 + m16];
    }
    b1[ct] = v;
  }
  float b1v[8], b2v[8];
  #pragma unroll
  for (int ct = 0; ct < 8; ++ct) {
    b1v[ct] = bg1[ct * 16 + m16];
    b2v[ct] = bg2[ct * 16 + m16];
  }

  const int ntiles = (NE + 63) >> 6;   // 3907
  const int hr = wv * 16 + quad * 4;   // C-layout row base in H stripe
  const int ar = wv * 16 + m16;        // A-frag / row-major row in H stripe

  for (int t = blockIdx.x; t < ntiles; t += gridDim.x) {
    const int p = (t << 6) + wv * 16 + m16;   // sorted position == out row

    // layer-1 A-frag: quad 0 holds the gathered ea row (k=0..7), rest zero
    bf16x8 a1 = bz8();
    if (quad == 0 && p < NE) {
      int e = sorted_t[p];
      f32x4 e0 = *(const f32x4*)(EA + (long)e * 8);
      f32x4 e1 = *(const f32x4*)(EA + (long)e * 8 + 4);
      #pragma unroll
      for (int j = 0; j < 4; ++j) { a1[j] = (__bf16)e0[j]; a1[4 + j] = (__bf16)e1[j]; }
    }
    f32x4 h[8];
    #pragma unroll
    for (int ct = 0; ct < 8; ++ct)
      h[ct] = __builtin_amdgcn_mfma_f32_16x16x32_bf16(a1, b1[ct], (f32x4){0.f,0.f,0.f,0.f}, 0, 0, 0);

    // bias + gelu in C-layout -> wave-private H stripe (in-order DS pipe)
    #pragma unroll
    for (int ct = 0; ct < 8; ++ct) {
      const int col = ct * 16 + m16;
      #pragma unroll
      for (int rg = 0; rg < 4; ++rg)
        H[hr + rg][col] = (__bf16)gelu_fast(h[ct][rg] + b1v[ct]);
    }
    asm volatile("s_waitcnt lgkmcnt(0)" ::: "memory");

    bf16x8 afr[4];
    #pragma unroll
    for (int kt = 0; kt < 4; ++kt)
      afr[kt] = *(const bf16x8*)&H[ar][kt * 32 + quad * 8];
    asm volatile("" ::: "memory");

    f32x4 acc[8];
    #pragma unroll
    for (int ct = 0; ct < 8; ++ct) acc[ct] = (f32x4){0.f, 0.f, 0.f, 0.f};
    #pragma unroll
    for (int kt = 0; kt < 4; ++kt) {
      #pragma unroll
      for (int ct = 0; ct < 8; ++ct) {
        bf16x8 bfr = *(const bf16x8*)&Wt[ct * 16 + m16][kt * 32 + quad * 8];
        acc[ct] = __builtin_amdgcn_mfma_f32_16x16x32_bf16(afr[kt], bfr, acc[ct], 0, 0, 0);
      }
    }

    // sigmoid: DIRECT C-layout global stores (no second LDS trip).
    // Per instr: m16 spans 16 contiguous cols (32 B), quad spans 4 rows.
    const long rowbase = (long)(t << 6) + hr;
    #pragma unroll
    for (int ct = 0; ct < 8; ++ct) {
      const int col = ct * 16 + m16;
      #pragma unroll
      for (int rg = 0; rg < 4; ++rg)
        out[(rowbase + rg) * 128 + col] = (__bf16)sigmoid_fast(acc[ct][rg] + b2v[ct]);
    }
  }
}

// ---------------------------------------------------------------------------
// Counting sort of edges by destination node (both edge types per launch).
// scatter2 also materializes ssrc[p] = si[sorted[p]] (drops a dependency
// level in the aggregate).
// ---------------------------------------------------------------------------
__global__ __launch_bounds__(256)
void histo2(const int* __restrict__ di_t, const int* __restrict__ di_r,
            int* __restrict__ cnt_dis, int* __restrict__ cnt_drug, int half) {
  int b = blockIdx.x;
  if (b < half) {
    int i = b * 256 + threadIdx.x;
    if (i < NE) atomicAdd(&cnt_dis[di_t[i]], 1);
  } else {
    int i = (b - half) * 256 + threadIdx.x;
    if (i < NE) atomicAdd(&cnt_drug[di_r[i]], 1);
  }
}

__global__ __launch_bounds__(256)
void scatter2(const int* __restrict__ di_t, const int* __restrict__ di_r,
              const int* __restrict__ si_t, const int* __restrict__ si_r,
              int* __restrict__ cur_dis, int* __restrict__ cur_drug,
              int* __restrict__ sorted_t, int* __restrict__ ssrc_t,
              int* __restrict__ ssrc_r, int half) {
  int b = blockIdx.x;
  if (b < half) {
    int i = b * 256 + threadIdx.x;
    if (i < NE) {
      int p = atomicAdd(&cur_dis[di_t[i]], 1);
      sorted_t[p] = i;
      ssrc_t[p] = si_t[i];
    }
  } else {
    int i = (b - half) * 256 + threadIdx.x;
    if (i < NE) {
      int p = atomicAdd(&cur_drug[di_r[i]], 1);
      ssrc_r[p] = si_r[i];
    }
  }
}

// ---------------------------------------------------------------------------
// Device-wide segmented exclusive scan over concatenated cnt_dis||cnt_drug.
// ---------------------------------------------------------------------------
__device__ __forceinline__ void seg_geom(int b, int& base, int& n, int& lb) {
  if (b < NB0) { base = 0;     n = 20000; lb = b; }
  else         { base = 20000; n = 50000; lb = b - NB0; }
}

__global__ __launch_bounds__(256)
void scan_partial(const int* __restrict__ cnt, int* __restrict__ bsum) {
  __shared__ int sh[256];
  int b = blockIdx.x, t = threadIdx.x;
  int base, n, lb; seg_geom(b, base, n, lb);
  int i = lb * 256 + t;
  sh[t] = (i < n) ? cnt[base + i] : 0;
  __syncthreads();
  for (int d = 1; d < 256; d <<= 1) {
    int vv = (t >= d) ? sh[t - d] : 0;
    __syncthreads();
    sh[t] += vv;
    __syncthreads();
  }
  if (t == 255) bsum[b] = sh[255];
}

__global__ __launch_bounds__(512)
void scan_block(const int* __restrict__ bsum, int* __restrict__ bexc) {
  __shared__ int v[512];
  __shared__ int f[512];
  int t = threadIdx.x;
  int own = (t < NBT) ? bsum[t] : 0;
  v[t] = own;
  f[t] = (t == 0 || t == NB0 || t >= NBT) ? 1 : 0;
  __syncthreads();
  for (int d = 1; d < 512; d <<= 1) {
    int vv = 0, ff = 1;
    if (t >= d) { vv = v[t - d]; ff = f[t - d]; }
    __syncthreads();
    if (t >= d && !f[t]) { v[t] += vv; f[t] |= ff; }
    __syncthreads();
  }
  if (t < NBT) bexc[t] = v[t] - own;   // exclusive within segment
}

__global__ __launch_bounds__(256)
void scan_final(const int* __restrict__ cnt, const int* __restrict__ bexc,
                int* __restrict__ offs, int* __restrict__ cursor) {
  __shared__ int sh[256];
  int b = blockIdx.x, t = threadIdx.x;
  int base, n, lb; seg_geom(b, base, n, lb);
  int i = lb * 256 + t;
  int own = (i < n) ? cnt[base + i] : 0;
  sh[t] = own;
  __syncthreads();
  for (int d = 1; d < 256; d <<= 1) {
    int vv = (t >= d) ? sh[t - d] : 0;
    __syncthreads();
    sh[t] += vv;
    __syncthreads();
  }
  int off = bexc[b] + sh[t] - own;
  if (i < n) { offs[base + i] = off; cursor[base + i] = off; }
}

// ---------------------------------------------------------------------------
// Merged gather-side aggregation, SCALARIZED control/address plane.
// One 64-lane wave per destination node; lane owns channels {2l, 2l+1}.
//  * batch-level WAVE-UNIFORM guards (m SGPR -> s_cbranch): no loads issued
//    past the last needed batch.
//  * 3-stage row pipeline: ids 3 batches ahead (SGPRs), rows in flight for
//    batches j+4 and j+8 while batch j computes.
//  * scalar clamps, DPP row_ror reduce, log2-domain exp, masked ex.
// ---------------------------------------------------------------------------
__global__ __launch_bounds__(256)
void aggregate2(const __bf16* __restrict__ Xs_t, const __bf16* __restrict__ Xd_t,
                const __bf16* __restrict__ Xs_r, const __bf16* __restrict__ Xd_r,
                const int* __restrict__ ssrc_t, const int* __restrict__ ssrc_r,
                const int* __restrict__ offs, const int* __restrict__ cnt,
                const __bf16* __restrict__ gate_s,
                const float* __restrict__ attn_t, const float* __restrict__ attn_r,
                __bf16* __restrict__ aggr_dis, __bf16* __restrict__ aggr_drug)
{
  const int gw0 = (int)((blockIdx.x * 256 + threadIdx.x) >> 6);
  if (gw0 >= N_DIS + N_DRUG) return;
  const int gw = __builtin_amdgcn_readfirstlane(gw0);   // wave-uniform -> SGPR
  const int lane = threadIdx.x & 63;
  const int c = lane * 2;
  const bool isDis = gw < N_DIS;
  const int node = isDis ? gw : gw - N_DIS;
  const __bf16* __restrict__ Xs = isDis ? Xs_t : Xs_r;
  const __bf16* __restrict__ Xd = isDis ? Xd_t : Xd_r;
  const int* __restrict__ ssrc = isDis ? ssrc_t : ssrc_r;
  const float* __restrict__ attn = isDis ? attn_t : attn_r;
  __bf16* __restrict__ outp = isDis ? aggr_dis : aggr_drug;
  const int Ns = isDis ? N_DRUG : N_DIS;

  const int start = __builtin_amdgcn_readfirstlane(offs[gw]);
  const int m     = __builtin_amdgcn_readfirstlane(cnt[gw]);

  // per-lane constants; 1/sqrt(HD) and log2(e) folded into the logit terms
  const float LOG2E = 1.4426950408889634f;
  f32x2 at = *(const f32x2*)(attn + c);
  bf16x2 xdb = *(const bf16x2*)(Xd + (size_t)node * 128 + c);
  const float xd0 = (float)xdb[0], xd1 = (float)xdb[1];
  const float xdl0 = xd0 * (0.17677669529663687f * LOG2E);
  const float xdl1 = xd1 * (0.17677669529663687f * LOG2E);
  const float at0 = at[0] * LOG2E, at1 = at[1] * LOG2E;

  // scalar source-id fetch: clamped index, value forced to SGPR, clamped to
  // a valid row so the gather address is always in initialized memory.
  auto sfetch = [&](int jn) -> int {
    int idx = start + jn;
    if (idx > NE - 1) idx = NE - 1;                     // scalar clamp
    int s = __builtin_amdgcn_readfirstlane(ssrc[idx]);
    return ((unsigned)s < (unsigned)Ns) ? s : 0;        // scalar clamp
  };
  auto row_load = [&](int s) -> bf16x2 {                // SGPR base + lane voff
    return *(const bf16x2*)(Xs + (size_t)s * 128 + c);
  };
  auto gate_load = [&](int jn) -> bf16x2 {              // sequential rows
    return *(const bf16x2*)(gate_s + (size_t)(start + jn) * 128 + c);
  };

  const bf16x2 z2 = {(__bf16)0.f, (__bf16)0.f};
  bf16x2 xa[4], ga[4], xb[4], gb[4];
  #pragma unroll
  for (int u = 0; u < 4; ++u) { xa[u] = z2; ga[u] = z2; xb[u] = z2; gb[u] = z2; }

  // ids for batches 0/1/2 — independent scalar loads, one lgkm wait covers all
  int s0[4], s1[4], s2[4];
  #pragma unroll
  for (int u = 0; u < 4; ++u) s0[u] = sfetch(u);
  #pragma unroll
  for (int u = 0; u < 4; ++u) s1[u] = sfetch(4 + u);
  #pragma unroll
  for (int u = 0; u < 4; ++u) s2[u] = sfetch(8 + u);

  // rows for batch 0 (always) and batch 1 (if it exists)
  #pragma unroll
  for (int u = 0; u < 4; ++u) {
    xa[u] = row_load(s0[u]);
    if (isDis) ga[u] = gate_load(u);
  }
  if (m > 4) {
    #pragma unroll
    for (int u = 0; u < 4; ++u) {
      xb[u] = row_load(s1[u]);
      if (isDis) gb[u] = gate_load(4 + u);
    }
  }

  float n0 = 0.f, n1 = 0.f, den = 0.f;

  for (int j = 0; j < m; j += 4) {
    // issue rows for batch j+8 (ids already in SGPRs); refill ids for j+12.
    // all guards wave-uniform (m, j scalar) -> no divergence, no waste.
    bf16x2 xc[4], gc[4];
    #pragma unroll
    for (int u = 0; u < 4; ++u) { xc[u] = z2; gc[u] = z2; }
    if (j + 8 < m) {
      #pragma unroll
      for (int u = 0; u < 4; ++u) {
        xc[u] = row_load(s2[u]);
        if (isDis) gc[u] = gate_load(j + 8 + u);
      }
    }
    if (j + 12 < m) {
      #pragma unroll
      for (int u = 0; u < 4; ++u) s2[u] = sfetch(j + 12 + u);
    }

    // compute batch j (4 edges, 2 channels/lane)
    float part[4], mm0[4], mm1[4];
    #pragma unroll
    for (int u = 0; u < 4; ++u) {
      float xs0 = (float)xa[u][0], xs1 = (float)xa[u][1];
      float m0 = xs0 + xd0, m1 = xs1 + xd1;
      if (isDis) { m0 *= (float)ga[u][0]; m1 *= (float)ga[u][1]; }
      mm0[u] = m0; mm1[u] = m1;
      part[u] = xs0 * xdl0 + xs1 * xdl1 + m0 * at0 + m1 * at1;  // log2 domain
    }
    // per-head (16-lane row) rotation all-reduce, 4 interleaved VALU chains
    #pragma unroll
    for (int u = 0; u < 4; ++u) part[u] += dpp_ror<1>(part[u]);
    #pragma unroll
    for (int u = 0; u < 4; ++u) part[u] += dpp_ror<2>(part[u]);
    #pragma unroll
    for (int u = 0; u < 4; ++u) part[u] += dpp_ror<4>(part[u]);
    #pragma unroll
    for (int u = 0; u < 4; ++u) part[u] += dpp_ror<8>(part[u]);

    #pragma unroll
    for (int u = 0; u < 4; ++u) {
      float ex = (j + u < m) ? __builtin_amdgcn_exp2f(part[u]) : 0.f;
      n0 += mm0[u] * ex;
      n1 += mm1[u] * ex;
      den += ex;
    }
    // rotate the 3-stage row pipeline
    #pragma unroll
    for (int u = 0; u < 4; ++u) {
      xa[u] = xb[u]; ga[u] = gb[u];
      xb[u] = xc[u]; gb[u] = gc[u];
    }
  }

  float r = __builtin_amdgcn_rcpf(den + 1e-16f);
  bf16x2 o;
  o[0] = (__bf16)(n0 * r);
  o[1] = (__bf16)(n1 * r);
  *(bf16x2*)(outp + (size_t)node * 128 + c) = o;
}

// ---------------------------------------------------------------------------
extern "C" void kernel_launch(void* const* d_in, const int* in_sizes, int n_in,
                              void* d_out, int out_size, void* d_ws, size_t ws_size,
                              hipStream_t stream)
{
  const float* x_drug  = (const float*)d_in[0];
  const float* x_dis   = (const float*)d_in[1];
  const float* ea      = (const float*)d_in[2];
  const int*   si_t    = (const int*)d_in[3];
  const int*   di_t    = (const int*)d_in[4];
  const int*   si_r    = (const int*)d_in[5];
  const int*   di_r    = (const int*)d_in[6];
  const float* Ws_t    = (const float*)d_in[7];
  const float* bs_t    = (const float*)d_in[8];
  const float* Wd_t    = (const float*)d_in[9];
  const float* bd_t    = (const float*)d_in[10];
  const float* attn_t  = (const float*)d_in[11];
  const float* Wg1     = (const float*)d_in[12];
  const float* bg1     = (const float*)d_in[13];
  const float* Wg2     = (const float*)d_in[14];
  const float* bg2     = (const float*)d_in[15];
  const float* Ws_r    = (const float*)d_in[16];
  const float* bs_r    = (const float*)d_in[17];
  const float* Wd_r    = (const float*)d_in[18];
  const float* bd_r    = (const float*)d_in[19];
  const float* attn_r  = (const float*)d_in[20];
  const float* Wo_drug = (const float*)d_in[21];
  const float* bo_drug = (const float*)d_in[22];
  const float* Wo_dis  = (const float*)d_in[23];
  const float* bo_dis  = (const float*)d_in[24];

  // workspace layout (~104 MB); X/gate tensors bf16.
  // aggr_dis aliases Xd_t, aggr_drug aliases Xd_r (row-for-row safe).
  __bf16* wsb      = (__bf16*)d_ws;
  __bf16* Xs_t     = wsb;                  // 50000*128
  __bf16* Xd_t     = Xs_t + 6400000;       // 20000*128 (-> aggr_dis)
  __bf16* Xs_r     = Xd_t + 2560000;       // 20000*128
  __bf16* Xd_r     = Xs_r + 2560000;       // 50000*128 (-> aggr_drug)
  __bf16* gate     = Xd_r + 6400000;       // NE_PAD*128, SORTED order
  int* cnt_dis    = (int*)(gate + (long)NE_PAD * 128);  // 20000  --+ contiguous:
  int* cnt_drug   = cnt_dis + 20000;       // 50000             | zeroed+scanned
  int* offs_dis   = cnt_drug + 50000;      // 20000             | as one region
  int* offs_drug  = offs_dis + 20000;      // 50000             |
  int* cur_dis    = offs_drug + 50000;     // 20000             |
  int* cur_drug   = cur_dis + 20000;       // 50000           --+
  int* sorted_t   = cur_drug + 50000;      // 250000 (gate kernel only)
  int* ssrc_t     = sorted_t + 250000;     // 250000
  int* ssrc_r     = ssrc_t + 250000;       // 250000
  int* bsum       = ssrc_r + 250000;       // 275
  int* bexc       = bsum + 512;            // 275

  __bf16* aggr_dis  = Xd_t;
  __bf16* aggr_drug = Xd_r;

  float* out_drug = (float*)d_out;
  float* out_dis  = out_drug + (long)N_DRUG * 128;

  hipMemsetAsync(cnt_dis, 0, 70000 * sizeof(int), stream);

  const int eb = (NE + 255) / 256;         // 977

  // counting sort by destination (both convs), device-wide 3-phase scan
  histo2<<<2 * eb, 256, 0, stream>>>(di_t, di_r, cnt_dis, cnt_drug, eb);
  scan_partial<<<NBT, 256, 0, stream>>>(cnt_dis, bsum);
  scan_block<<<1, 512, 0, stream>>>(bsum, bexc);
  scan_final<<<NBT, 256, 0, stream>>>(cnt_dis, bexc, offs_dis, cur_dis);
  scatter2<<<2 * eb, 256, 0, stream>>>(di_t, di_r, si_t, si_r, cur_dis, cur_drug,
                                       sorted_t, ssrc_t, ssrc_r, eb);

  // 4 node transforms, persistent per-segment blocks (tiles 782/313/313/782)
  Seg nd;
  nd.A[0] = x_drug; nd.W[0] = Ws_t; nd.bias[0] = bs_t; nd.out[0] = Xs_t; nd.M[0] = N_DRUG;
  nd.A[1] = x_dis;  nd.W[1] = Wd_t; nd.bias[1] = bd_t; nd.out[1] = Xd_t; nd.M[1] = N_DIS;
  nd.A[2] = x_dis;  nd.W[2] = Ws_r; nd.bias[2] = bs_r; nd.out[2] = Xs_r; nd.M[2] = N_DIS;
  nd.A[3] = x_drug; nd.W[3] = Wd_r; nd.bias[3] = bd_r; nd.out[3] = Xd_r; nd.M[3] = N_DRUG;
  nd.bstart[0] = 0; nd.bstart[1] = 274; nd.bstart[2] = 384; nd.bstart[3] = 494; nd.bstart[4] = 768;
  gemm_seg<0, 1><<<768, 256, 0, stream>>>(nd);

  // edge gate in sorted order: 768 blocks (3 blocks/CU at 52 KB LDS,
  // 12 waves/CU)
  gate_kernel<<<768, 256, 0, stream>>>(ea, Wg2, Wg1, bg1, bg2, sorted_t, gate);

  // merged gather-side aggregation: 70000 waves, one per destination node
  aggregate2<<<(N_DIS + N_DRUG + 3) / 4, 256, 0, stream>>>(
      Xs_t, Xd_t, Xs_r, Xd_r, ssrc_t, ssrc_r, offs_dis, cnt_dis,
      gate, attn_t, attn_r, aggr_dis, aggr_drug);

  // 2 output linears, persistent per-segment blocks (tiles 782/313)
  Seg od;
  od.A[0] = aggr_drug; od.W[0] = Wo_drug; od.bias[0] = bo_drug; od.out[0] = out_drug; od.M[0] = N_DRUG;
  od.A[1] = aggr_dis;  od.W[1] = Wo_dis;  od.bias[1] = bo_dis;  od.out[1] = out_dis;  od.M[1] = N_DIS;
  od.A[2] = od.A[1];   od.W[2] = od.W[1]; od.bias[2] = od.bias[1]; od.out[2] = od.out[1]; od.M[2] = N_DIS;
  od.A[3] = od.A[1];   od.W[3] = od.W[1]; od.bias[3] = od.bias[1]; od.out[3] = od.out[1]; od.M[3] = N_DIS;
  od.bstart[0] = 0; od.bstart[1] = 548; od.bstart[2] = 768; od.bstart[3] = 768; od.bstart[4] = 768;
  gemm_seg<1, 0><<<768, 256, 0, stream>>>(od);
}

// Round 9
// 317.301 us; speedup vs baseline: 1.0588x; 1.0241x over previous
//
#include <hip/hip_runtime.h>
#include <hip/hip_bf16.h>
#include <math.h>

#define N_DRUG 50000
#define N_DIS  20000
#define NE     250000
#define NE_PAD 250048   // 3907 full 64-row tiles (gate stored without bounds checks)

// scan geometry: segment 0 = cnt_dis (20000), segment 1 = cnt_drug (50000)
#define NB0 79     // ceil(20000/256)
#define NBT 275    // NB0 + ceil(50000/256)

typedef __bf16 bf16x8 __attribute__((ext_vector_type(8)));
typedef __bf16 bf16x4 __attribute__((ext_vector_type(4)));
typedef __bf16 bf16x2 __attribute__((ext_vector_type(2)));
typedef float  f32x4  __attribute__((ext_vector_type(4)));
typedef float  f32x2  __attribute__((ext_vector_type(2)));

__device__ __forceinline__ bf16x8 bz8() {
  bf16x8 v;
  #pragma unroll
  for (int j = 0; j < 8; ++j) v[j] = (__bf16)0.f;
  return v;
}

// Fast gelu: erf via Abramowitz-Stegun 7.1.27 (|erf err| <= 5e-4), 1/sqrt(2)
// folded into coefficients. gelu(x)=0.5*x*(2-p^-4) for x>=0, 0.5*x*p^-4 else.
__device__ __forceinline__ float gelu_fast(float x) {
  float ax = fabsf(x);
  float t = fmaf(ax, 0.019527f, 3.43654e-4f);
  t = fmaf(ax, t, 0.1151945f);
  t = fmaf(ax, t, 0.1968564f);
  float p = fmaf(ax, t, 1.0f);
  float p2 = p * p;
  float p4 = p2 * p2;
  float r = __builtin_amdgcn_rcpf(p4);
  float sel = (x >= 0.f) ? (2.0f - r) : r;
  return 0.5f * x * sel;
}

__device__ __forceinline__ float sigmoid_fast(float v) {
  return __builtin_amdgcn_rcpf(1.0f + __expf(-v));
}

// DPP row-rotate (within the 16-lane row): VALU-pipe lane exchange, no LDS.
// ctrl 0x120|N = ROW_ROR:N. Four levels (1,2,4,8) = rotation all-reduce.
template <int N>
__device__ __forceinline__ float dpp_ror(float v) {
  int r = __builtin_amdgcn_update_dpp(0, __builtin_bit_cast(int, v),
                                      0x120 | N, 0xF, 0xF, false);
  return __builtin_bit_cast(float, r);
}

// ---------------------------------------------------------------------------
// Persistent multi-segment [M,128] @ [128,128] GEMM.
// Per-segment block partition (bstart[5]); each block stages its segment's W
// to LDS ONCE, then grid-strides tiles. A-fragments load directly from global
// into registers, software-pipelined one tile ahead (no barriers in the loop).
// ---------------------------------------------------------------------------
struct Seg {
  const void* A[4];
  const float* W[4];
  const float* bias[4];
  void* out[4];
  int M[4];
  int bstart[5];
};

template <int AIN_BF16, int OUT_BF16>
__global__ __launch_bounds__(256)
void gemm_seg(Seg d)
{
  __shared__ __bf16 Wt[128][136];   // W transposed: Wt[n][k]

  const int b = blockIdx.x;
  const int sidx = (b >= d.bstart[3]) ? 3 : (b >= d.bstart[2]) ? 2
                 : (b >= d.bstart[1]) ? 1 : 0;
  const int nb = d.bstart[sidx + 1] - d.bstart[sidx];
  const int lb = b - d.bstart[sidx];
  const float* W = d.W[sidx];
  const float* bias = d.bias[sidx];
  const int M = d.M[sidx];
  const int ntiles = (M + 63) >> 6;
  const int tid = threadIdx.x;
  const int wv = tid >> 6, lane = tid & 63;
  const int m16 = lane & 15, quad = lane >> 4;

  for (int idx = tid; idx < 16384; idx += 256) {
    int k = idx >> 7, n = idx & 127;
    Wt[n][k] = (__bf16)W[idx];
  }
  __syncthreads();   // the only barrier: Wt visible to all waves

  float bv[8];
  #pragma unroll
  for (int ct = 0; ct < 8; ++ct) bv[ct] = bias[ct * 16 + m16];

  auto load_afr = [&](int t, bf16x8* afr) {
    const int arow = (t << 6) + wv * 16 + m16;
    const bool ok = (t < ntiles) && (arow < M);
    if (AIN_BF16) {
      const __bf16* ap = (const __bf16*)d.A[sidx] + (long)arow * 128 + quad * 8;
      #pragma unroll
      for (int kt = 0; kt < 4; ++kt)
        afr[kt] = ok ? *(const bf16x8*)(ap + kt * 32) : bz8();
    } else {
      const float* ap = (const float*)d.A[sidx] + (long)arow * 128 + quad * 8;
      #pragma unroll
      for (int kt = 0; kt < 4; ++kt) {
        bf16x8 v = bz8();
        if (ok) {
          f32x4 lo = *(const f32x4*)(ap + kt * 32);
          f32x4 hi = *(const f32x4*)(ap + kt * 32 + 4);
          #pragma unroll
          for (int j = 0; j < 4; ++j) { v[j] = (__bf16)lo[j]; v[4 + j] = (__bf16)hi[j]; }
        }
        afr[kt] = v;
      }
    }
  };

  bf16x8 afr[4];
  if (lb < ntiles) load_afr(lb, afr);

  for (int t = lb; t < ntiles; t += nb) {
    bf16x8 nafr[4];
    load_afr(t + nb, nafr);   // in flight during this tile's MFMA + stores

    f32x4 acc[8];
    #pragma unroll
    for (int ct = 0; ct < 8; ++ct) acc[ct] = (f32x4){0.f, 0.f, 0.f, 0.f};
    #pragma unroll
    for (int kt = 0; kt < 4; ++kt) {
      #pragma unroll
      for (int ct = 0; ct < 8; ++ct) {
        bf16x8 bfr = *(const bf16x8*)&Wt[ct * 16 + m16][kt * 32 + quad * 8];
        acc[ct] = __builtin_amdgcn_mfma_f32_16x16x32_bf16(afr[kt], bfr, acc[ct], 0, 0, 0);
      }
    }

    // C/D layout: col=lane&15, row=quad*4+reg
    const int rb = (t << 6) + wv * 16 + quad * 4;
    #pragma unroll
    for (int ct = 0; ct < 8; ++ct) {
      const int col = ct * 16 + m16;
      #pragma unroll
      for (int rg = 0; rg < 4; ++rg) {
        int gr = rb + rg;
        if (gr < M) {
          float v = acc[ct][rg] + bv[ct];
          if (OUT_BF16) ((__bf16*)d.out[sidx])[(long)gr * 128 + col] = (__bf16)v;
          else          ((float*)d.out[sidx])[(long)gr * 128 + col] = v;
        }
      }
    }
    #pragma unroll
    for (int kt = 0; kt < 4; ++kt) afr[kt] = nafr[kt];
  }
}

// ---------------------------------------------------------------------------
// Edge gate, SORTED ORDER: row p of `out` is the gate of edge sorted_t[p],
// so the aggregate reads it fully sequentially. ea rows gathered (32 B,
// hidden under MFMA + TLP). 768 blocks (3 blocks/CU at 52 KB LDS ->
// 12 waves/CU). Sigmoid phase stores DIRECT C-layout to global (no second
// LDS trip); gelu LDS trip stays (needed for layer-2 A-frag relayout).
// ---------------------------------------------------------------------------
__global__ __launch_bounds__(256)
void gate_kernel(const float* __restrict__ EA, const float* __restrict__ W2,
                 const float* __restrict__ Wg1, const float* __restrict__ bg1,
                 const float* __restrict__ bg2, const int* __restrict__ sorted_t,
                 __bf16* __restrict__ out)
{
  __shared__ __bf16 Wt[128][136];
  __shared__ __bf16 H[64][136];
  const int tid = threadIdx.x;
  const int wv = tid >> 6, lane = tid & 63;
  const int m16 = lane & 15, quad = lane >> 4;

  for (int idx = tid; idx < 16384; idx += 256) {
    int k = idx >> 7, n = idx & 127;
    Wt[n][k] = (__bf16)W2[idx];
  }
  __syncthreads();

  // layer-1 B-fragments: B[n=ct*16+m16][k=quad*8+j] = Wg1[k][n], k<8 real
  bf16x8 b1[8];
  #pragma unroll
  for (int ct = 0; ct < 8; ++ct) {
    bf16x8 v = bz8();
    if (quad == 0) {
      #pragma unroll
      for (int j = 0; j < 8; ++j) v[j] = (__bf16)Wg1[j * 128 + ct * 16 + m16];
    }
    b1[ct] = v;
  }
  float b1v[8], b2v[8];
  #pragma unroll
  for (int ct = 0; ct < 8; ++ct) {
    b1v[ct] = bg1[ct * 16 + m16];
    b2v[ct] = bg2[ct * 16 + m16];
  }

  const int ntiles = (NE + 63) >> 6;   // 3907
  const int hr = wv * 16 + quad * 4;   // C-layout row base in H stripe
  const int ar = wv * 16 + m16;        // A-frag / row-major row in H stripe

  for (int t = blockIdx.x; t < ntiles; t += gridDim.x) {
    const int p = (t << 6) + wv * 16 + m16;   // sorted position == out row

    // layer-1 A-frag: quad 0 holds the gathered ea row (k=0..7), rest zero
    bf16x8 a1 = bz8();
    if (quad == 0 && p < NE) {
      int e = sorted_t[p];
      f32x4 e0 = *(const f32x4*)(EA + (long)e * 8);
      f32x4 e1 = *(const f32x4*)(EA + (long)e * 8 + 4);
      #pragma unroll
      for (int j = 0; j < 4; ++j) { a1[j] = (__bf16)e0[j]; a1[4 + j] = (__bf16)e1[j]; }
    }
    f32x4 h[8];
    #pragma unroll
    for (int ct = 0; ct < 8; ++ct)
      h[ct] = __builtin_amdgcn_mfma_f32_16x16x32_bf16(a1, b1[ct], (f32x4){0.f,0.f,0.f,0.f}, 0, 0, 0);

    // bias + gelu in C-layout -> wave-private H stripe (in-order DS pipe)
    #pragma unroll
    for (int ct = 0; ct < 8; ++ct) {
      const int col = ct * 16 + m16;
      #pragma unroll
      for (int rg = 0; rg < 4; ++rg)
        H[hr + rg][col] = (__bf16)gelu_fast(h[ct][rg] + b1v[ct]);
    }
    asm volatile("s_waitcnt lgkmcnt(0)" ::: "memory");

    bf16x8 afr[4];
    #pragma unroll
    for (int kt = 0; kt < 4; ++kt)
      afr[kt] = *(const bf16x8*)&H[ar][kt * 32 + quad * 8];
    asm volatile("" ::: "memory");

    f32x4 acc[8];
    #pragma unroll
    for (int ct = 0; ct < 8; ++ct) acc[ct] = (f32x4){0.f, 0.f, 0.f, 0.f};
    #pragma unroll
    for (int kt = 0; kt < 4; ++kt) {
      #pragma unroll
      for (int ct = 0; ct < 8; ++ct) {
        bf16x8 bfr = *(const bf16x8*)&Wt[ct * 16 + m16][kt * 32 + quad * 8];
        acc[ct] = __builtin_amdgcn_mfma_f32_16x16x32_bf16(afr[kt], bfr, acc[ct], 0, 0, 0);
      }
    }

    // sigmoid: DIRECT C-layout global stores (no second LDS trip).
    // Per instr: m16 spans 16 contiguous cols (32 B), quad spans 4 rows.
    const long rowbase = (long)(t << 6) + hr;
    #pragma unroll
    for (int ct = 0; ct < 8; ++ct) {
      const int col = ct * 16 + m16;
      #pragma unroll
      for (int rg = 0; rg < 4; ++rg)
        out[(rowbase + rg) * 128 + col] = (__bf16)sigmoid_fast(acc[ct][rg] + b2v[ct]);
    }
  }
}

// ---------------------------------------------------------------------------
// Counting sort of edges by destination node (both edge types per launch).
// scatter2 also materializes ssrc[p] = si[sorted[p]] (drops a dependency
// level in the aggregate).
// ---------------------------------------------------------------------------
__global__ __launch_bounds__(256)
void histo2(const int* __restrict__ di_t, const int* __restrict__ di_r,
            int* __restrict__ cnt_dis, int* __restrict__ cnt_drug, int half) {
  int b = blockIdx.x;
  if (b < half) {
    int i = b * 256 + threadIdx.x;
    if (i < NE) atomicAdd(&cnt_dis[di_t[i]], 1);
  } else {
    int i = (b - half) * 256 + threadIdx.x;
    if (i < NE) atomicAdd(&cnt_drug[di_r[i]], 1);
  }
}

__global__ __launch_bounds__(256)
void scatter2(const int* __restrict__ di_t, const int* __restrict__ di_r,
              const int* __restrict__ si_t, const int* __restrict__ si_r,
              int* __restrict__ cur_dis, int* __restrict__ cur_drug,
              int* __restrict__ sorted_t, int* __restrict__ ssrc_t,
              int* __restrict__ ssrc_r, int half) {
  int b = blockIdx.x;
  if (b < half) {
    int i = b * 256 + threadIdx.x;
    if (i < NE) {
      int p = atomicAdd(&cur_dis[di_t[i]], 1);
      sorted_t[p] = i;
      ssrc_t[p] = si_t[i];
    }
  } else {
    int i = (b - half) * 256 + threadIdx.x;
    if (i < NE) {
      int p = atomicAdd(&cur_drug[di_r[i]], 1);
      ssrc_r[p] = si_r[i];
    }
  }
}

// ---------------------------------------------------------------------------
// Device-wide segmented exclusive scan over concatenated cnt_dis||cnt_drug.
// R9: 2 kernels instead of 3 — scan_block (single 512-thread block, pure
// serial launch latency on the critical path) is deleted; every scan_final2
// block redundantly computes the 275-entry segmented block-prefix from bsum
// in LDS (L2-broadcast read + flag-segmented Hillis-Steele, 2 elems/thread,
// ~1-2 us absorbed in parallel across 275 blocks).
// ---------------------------------------------------------------------------
__device__ __forceinline__ void seg_geom(int b, int& base, int& n, int& lb) {
  if (b < NB0) { base = 0;     n = 20000; lb = b; }
  else         { base = 20000; n = 50000; lb = b - NB0; }
}

__global__ __launch_bounds__(256)
void scan_partial(const int* __restrict__ cnt, int* __restrict__ bsum) {
  __shared__ int sh[256];
  int b = blockIdx.x, t = threadIdx.x;
  int base, n, lb; seg_geom(b, base, n, lb);
  int i = lb * 256 + t;
  sh[t] = (i < n) ? cnt[base + i] : 0;
  __syncthreads();
  for (int d = 1; d < 256; d <<= 1) {
    int vv = (t >= d) ? sh[t - d] : 0;
    __syncthreads();
    sh[t] += vv;
    __syncthreads();
  }
  if (t == 255) bsum[b] = sh[255];
}

__global__ __launch_bounds__(256)
void scan_final2(const int* __restrict__ cnt, const int* __restrict__ bsum,
                 int* __restrict__ offs, int* __restrict__ cursor) {
  __shared__ int v[512];
  __shared__ int f[512];
  __shared__ int sh[256];
  const int b = blockIdx.x, t = threadIdx.x;

  // ---- redundant segmented block-prefix over bsum[0..NBT) (2 elems/thread)
  for (int i = t; i < 512; i += 256) {
    v[i] = (i < NBT) ? bsum[i] : 0;
    f[i] = (i == 0 || i == NB0 || i >= NBT) ? 1 : 0;
  }
  __syncthreads();
  for (int d = 1; d < 512; d <<= 1) {
    const int i0 = t, i1 = t + 256;
    int vv0 = 0, ff0 = 1, vv1 = 0, ff1 = 1;
    if (i0 >= d) { vv0 = v[i0 - d]; ff0 = f[i0 - d]; }
    if (i1 >= d) { vv1 = v[i1 - d]; ff1 = f[i1 - d]; }
    __syncthreads();
    if (i0 >= d && !f[i0]) { v[i0] += vv0; f[i0] |= ff0; }
    if (i1 >= d && !f[i1]) { v[i1] += vv1; f[i1] |= ff1; }
    __syncthreads();
  }
  // exclusive prefix for THIS block: inclusive v[b] minus own bsum[b]
  const int bexc_b = v[b] - bsum[b];

  // ---- local 256-element scan (identical to old scan_final)
  int base, n, lb; seg_geom(b, base, n, lb);
  int i = lb * 256 + t;
  int own = (i < n) ? cnt[base + i] : 0;
  sh[t] = own;
  __syncthreads();
  for (int d = 1; d < 256; d <<= 1) {
    int vv = (t >= d) ? sh[t - d] : 0;
    __syncthreads();
    sh[t] += vv;
    __syncthreads();
  }
  int off = bexc_b + sh[t] - own;
  if (i < n) { offs[base + i] = off; cursor[base + i] = off; }
}

// ---------------------------------------------------------------------------
// Merged gather-side aggregation, SCALARIZED control/address plane.
// One 64-lane wave per destination node; lane owns channels {2l, 2l+1}.
//  * batch-level WAVE-UNIFORM guards (m SGPR -> s_cbranch): no loads issued
//    past the last needed batch.
//  * 3-stage row pipeline: ids 3 batches ahead (SGPRs), rows in flight for
//    batches j+4 and j+8 while batch j computes.
//  * scalar clamps, DPP row_ror reduce, log2-domain exp, masked ex.
// ---------------------------------------------------------------------------
__global__ __launch_bounds__(256)
void aggregate2(const __bf16* __restrict__ Xs_t, const __bf16* __restrict__ Xd_t,
                const __bf16* __restrict__ Xs_r, const __bf16* __restrict__ Xd_r,
                const int* __restrict__ ssrc_t, const int* __restrict__ ssrc_r,
                const int* __restrict__ offs, const int* __restrict__ cnt,
                const __bf16* __restrict__ gate_s,
                const float* __restrict__ attn_t, const float* __restrict__ attn_r,
                __bf16* __restrict__ aggr_dis, __bf16* __restrict__ aggr_drug)
{
  const int gw0 = (int)((blockIdx.x * 256 + threadIdx.x) >> 6);
  if (gw0 >= N_DIS + N_DRUG) return;
  const int gw = __builtin_amdgcn_readfirstlane(gw0);   // wave-uniform -> SGPR
  const int lane = threadIdx.x & 63;
  const int c = lane * 2;
  const bool isDis = gw < N_DIS;
  const int node = isDis ? gw : gw - N_DIS;
  const __bf16* __restrict__ Xs = isDis ? Xs_t : Xs_r;
  const __bf16* __restrict__ Xd = isDis ? Xd_t : Xd_r;
  const int* __restrict__ ssrc = isDis ? ssrc_t : ssrc_r;
  const float* __restrict__ attn = isDis ? attn_t : attn_r;
  __bf16* __restrict__ outp = isDis ? aggr_dis : aggr_drug;
  const int Ns = isDis ? N_DRUG : N_DIS;

  const int start = __builtin_amdgcn_readfirstlane(offs[gw]);
  const int m     = __builtin_amdgcn_readfirstlane(cnt[gw]);

  // per-lane constants; 1/sqrt(HD) and log2(e) folded into the logit terms
  const float LOG2E = 1.4426950408889634f;
  f32x2 at = *(const f32x2*)(attn + c);
  bf16x2 xdb = *(const bf16x2*)(Xd + (size_t)node * 128 + c);
  const float xd0 = (float)xdb[0], xd1 = (float)xdb[1];
  const float xdl0 = xd0 * (0.17677669529663687f * LOG2E);
  const float xdl1 = xd1 * (0.17677669529663687f * LOG2E);
  const float at0 = at[0] * LOG2E, at1 = at[1] * LOG2E;

  // scalar source-id fetch: clamped index, value forced to SGPR, clamped to
  // a valid row so the gather address is always in initialized memory.
  auto sfetch = [&](int jn) -> int {
    int idx = start + jn;
    if (idx > NE - 1) idx = NE - 1;                     // scalar clamp
    int s = __builtin_amdgcn_readfirstlane(ssrc[idx]);
    return ((unsigned)s < (unsigned)Ns) ? s : 0;        // scalar clamp
  };
  auto row_load = [&](int s) -> bf16x2 {                // SGPR base + lane voff
    return *(const bf16x2*)(Xs + (size_t)s * 128 + c);
  };
  auto gate_load = [&](int jn) -> bf16x2 {              // sequential rows
    return *(const bf16x2*)(gate_s + (size_t)(start + jn) * 128 + c);
  };

  const bf16x2 z2 = {(__bf16)0.f, (__bf16)0.f};
  bf16x2 xa[4], ga[4], xb[4], gb[4];
  #pragma unroll
  for (int u = 0; u < 4; ++u) { xa[u] = z2; ga[u] = z2; xb[u] = z2; gb[u] = z2; }

  // ids for batches 0/1/2 — independent scalar loads, one lgkm wait covers all
  int s0[4], s1[4], s2[4];
  #pragma unroll
  for (int u = 0; u < 4; ++u) s0[u] = sfetch(u);
  #pragma unroll
  for (int u = 0; u < 4; ++u) s1[u] = sfetch(4 + u);
  #pragma unroll
  for (int u = 0; u < 4; ++u) s2[u] = sfetch(8 + u);

  // rows for batch 0 (always) and batch 1 (if it exists)
  #pragma unroll
  for (int u = 0; u < 4; ++u) {
    xa[u] = row_load(s0[u]);
    if (isDis) ga[u] = gate_load(u);
  }
  if (m > 4) {
    #pragma unroll
    for (int u = 0; u < 4; ++u) {
      xb[u] = row_load(s1[u]);
      if (isDis) gb[u] = gate_load(4 + u);
    }
  }

  float n0 = 0.f, n1 = 0.f, den = 0.f;

  for (int j = 0; j < m; j += 4) {
    // issue rows for batch j+8 (ids already in SGPRs); refill ids for j+12.
    // all guards wave-uniform (m, j scalar) -> no divergence, no waste.
    bf16x2 xc[4], gc[4];
    #pragma unroll
    for (int u = 0; u < 4; ++u) { xc[u] = z2; gc[u] = z2; }
    if (j + 8 < m) {
      #pragma unroll
      for (int u = 0; u < 4; ++u) {
        xc[u] = row_load(s2[u]);
        if (isDis) gc[u] = gate_load(j + 8 + u);
      }
    }
    if (j + 12 < m) {
      #pragma unroll
      for (int u = 0; u < 4; ++u) s2[u] = sfetch(j + 12 + u);
    }

    // compute batch j (4 edges, 2 channels/lane)
    float part[4], mm0[4], mm1[4];
    #pragma unroll
    for (int u = 0; u < 4; ++u) {
      float xs0 = (float)xa[u][0], xs1 = (float)xa[u][1];
      float m0 = xs0 + xd0, m1 = xs1 + xd1;
      if (isDis) { m0 *= (float)ga[u][0]; m1 *= (float)ga[u][1]; }
      mm0[u] = m0; mm1[u] = m1;
      part[u] = xs0 * xdl0 + xs1 * xdl1 + m0 * at0 + m1 * at1;  // log2 domain
    }
    // per-head (16-lane row) rotation all-reduce, 4 interleaved VALU chains
    #pragma unroll
    for (int u = 0; u < 4; ++u) part[u] += dpp_ror<1>(part[u]);
    #pragma unroll
    for (int u = 0; u < 4; ++u) part[u] += dpp_ror<2>(part[u]);
    #pragma unroll
    for (int u = 0; u < 4; ++u) part[u] += dpp_ror<4>(part[u]);
    #pragma unroll
    for (int u = 0; u < 4; ++u) part[u] += dpp_ror<8>(part[u]);

    #pragma unroll
    for (int u = 0; u < 4; ++u) {
      float ex = (j + u < m) ? __builtin_amdgcn_exp2f(part[u]) : 0.f;
      n0 += mm0[u] * ex;
      n1 += mm1[u] * ex;
      den += ex;
    }
    // rotate the 3-stage row pipeline
    #pragma unroll
    for (int u = 0; u < 4; ++u) {
      xa[u] = xb[u]; ga[u] = gb[u];
      xb[u] = xc[u]; gb[u] = gc[u];
    }
  }

  float r = __builtin_amdgcn_rcpf(den + 1e-16f);
  bf16x2 o;
  o[0] = (__bf16)(n0 * r);
  o[1] = (__bf16)(n1 * r);
  *(bf16x2*)(outp + (size_t)node * 128 + c) = o;
}

// ---------------------------------------------------------------------------
extern "C" void kernel_launch(void* const* d_in, const int* in_sizes, int n_in,
                              void* d_out, int out_size, void* d_ws, size_t ws_size,
                              hipStream_t stream)
{
  const float* x_drug  = (const float*)d_in[0];
  const float* x_dis   = (const float*)d_in[1];
  const float* ea      = (const float*)d_in[2];
  const int*   si_t    = (const int*)d_in[3];
  const int*   di_t    = (const int*)d_in[4];
  const int*   si_r    = (const int*)d_in[5];
  const int*   di_r    = (const int*)d_in[6];
  const float* Ws_t    = (const float*)d_in[7];
  const float* bs_t    = (const float*)d_in[8];
  const float* Wd_t    = (const float*)d_in[9];
  const float* bd_t    = (const float*)d_in[10];
  const float* attn_t  = (const float*)d_in[11];
  const float* Wg1     = (const float*)d_in[12];
  const float* bg1     = (const float*)d_in[13];
  const float* Wg2     = (const float*)d_in[14];
  const float* bg2     = (const float*)d_in[15];
  const float* Ws_r    = (const float*)d_in[16];
  const float* bs_r    = (const float*)d_in[17];
  const float* Wd_r    = (const float*)d_in[18];
  const float* bd_r    = (const float*)d_in[19];
  const float* attn_r  = (const float*)d_in[20];
  const float* Wo_drug = (const float*)d_in[21];
  const float* bo_drug = (const float*)d_in[22];
  const float* Wo_dis  = (const float*)d_in[23];
  const float* bo_dis  = (const float*)d_in[24];

  // workspace layout (~104 MB); X/gate tensors bf16.
  // aggr_dis aliases Xd_t, aggr_drug aliases Xd_r (row-for-row safe).
  __bf16* wsb      = (__bf16*)d_ws;
  __bf16* Xs_t     = wsb;                  // 50000*128
  __bf16* Xd_t     = Xs_t + 6400000;       // 20000*128 (-> aggr_dis)
  __bf16* Xs_r     = Xd_t + 2560000;       // 20000*128
  __bf16* Xd_r     = Xs_r + 2560000;       // 50000*128 (-> aggr_drug)
  __bf16* gate     = Xd_r + 6400000;       // NE_PAD*128, SORTED order
  int* cnt_dis    = (int*)(gate + (long)NE_PAD * 128);  // 20000  --+ contiguous:
  int* cnt_drug   = cnt_dis + 20000;       // 50000             | zeroed+scanned
  int* offs_dis   = cnt_drug + 50000;      // 20000             | as one region
  int* offs_drug  = offs_dis + 20000;      // 50000             |
  int* cur_dis    = offs_drug + 50000;     // 20000             |
  int* cur_drug   = cur_dis + 20000;       // 50000           --+
  int* sorted_t   = cur_drug + 50000;      // 250000 (gate kernel only)
  int* ssrc_t     = sorted_t + 250000;     // 250000
  int* ssrc_r     = ssrc_t + 250000;       // 250000
  int* bsum       = ssrc_r + 250000;       // 275
  int* bexc       = bsum + 512;            // 275 (unused after R9 fusion)

  __bf16* aggr_dis  = Xd_t;
  __bf16* aggr_drug = Xd_r;

  float* out_drug = (float*)d_out;
  float* out_dis  = out_drug + (long)N_DRUG * 128;

  hipMemsetAsync(cnt_dis, 0, 70000 * sizeof(int), stream);

  const int eb = (NE + 255) / 256;         // 977

  // counting sort by destination (both convs), device-wide 2-phase scan
  // (block-prefix computed redundantly per block in scan_final2)
  histo2<<<2 * eb, 256, 0, stream>>>(di_t, di_r, cnt_dis, cnt_drug, eb);
  scan_partial<<<NBT, 256, 0, stream>>>(cnt_dis, bsum);
  scan_final2<<<NBT, 256, 0, stream>>>(cnt_dis, bsum, offs_dis, cur_dis);
  scatter2<<<2 * eb, 256, 0, stream>>>(di_t, di_r, si_t, si_r, cur_dis, cur_drug,
                                       sorted_t, ssrc_t, ssrc_r, eb);

  // 4 node transforms, persistent per-segment blocks (tiles 782/313/313/782)
  Seg nd;
  nd.A[0] = x_drug; nd.W[0] = Ws_t; nd.bias[0] = bs_t; nd.out[0] = Xs_t; nd.M[0] = N_DRUG;
  nd.A[1] = x_dis;  nd.W[1] = Wd_t; nd.bias[1] = bd_t; nd.out[1] = Xd_t; nd.M[1] = N_DIS;
  nd.A[2] = x_dis;  nd.W[2] = Ws_r; nd.bias[2] = bs_r; nd.out[2] = Xs_r; nd.M[2] = N_DIS;
  nd.A[3] = x_drug; nd.W[3] = Wd_r; nd.bias[3] = bd_r; nd.out[3] = Xd_r; nd.M[3] = N_DRUG;
  nd.bstart[0] = 0; nd.bstart[1] = 274; nd.bstart[2] = 384; nd.bstart[3] = 494; nd.bstart[4] = 768;
  gemm_seg<0, 1><<<768, 256, 0, stream>>>(nd);

  // edge gate in sorted order: 768 blocks (3 blocks/CU at 52 KB LDS,
  // 12 waves/CU)
  gate_kernel<<<768, 256, 0, stream>>>(ea, Wg2, Wg1, bg1, bg2, sorted_t, gate);

  // merged gather-side aggregation: 70000 waves, one per destination node
  aggregate2<<<(N_DIS + N_DRUG + 3) / 4, 256, 0, stream>>>(
      Xs_t, Xd_t, Xs_r, Xd_r, ssrc_t, ssrc_r, offs_dis, cnt_dis,
      gate, attn_t, attn_r, aggr_dis, aggr_drug);

  // 2 output linears, persistent per-segment blocks (tiles 782/313)
  Seg od;
  od.A[0] = aggr_drug; od.W[0] = Wo_drug; od.bias[0] = bo_drug; od.out[0] = out_drug; od.M[0] = N_DRUG;
  od.A[1] = aggr_dis;  od.W[1] = Wo_dis;  od.bias[1] = bo_dis;  od.out[1] = out_dis;  od.M[1] = N_DIS;
  od.A[2] = od.A[1];   od.W[2] = od.W[1]; od.bias[2] = od.bias[1]; od.out[2] = od.out[1]; od.M[2] = N_DIS;
  od.A[3] = od.A[1];   od.W[3] = od.W[1]; od.bias[3] = od.bias[1]; od.out[3] = od.out[1]; od.M[3] = N_DIS;
  od.bstart[0] = 0; od.bstart[1] = 548; od.bstart[2] = 768; od.bstart[3] = 768; od.bstart[4] = 768;
  gemm_seg<1, 0><<<768, 256, 0, stream>>>(od);
}

// Round 10
// 316.704 us; speedup vs baseline: 1.0608x; 1.0019x over previous
//
#include <hip/hip_runtime.h>
#include <hip/hip_bf16.h>
#include <math.h>

#define N_DRUG 50000
#define N_DIS  20000
#define NE     250000
#define NE_PAD 250048   // 3907 full 64-row tiles (gate stored without bounds checks)

// scan geometry: segment 0 = cnt_dis (20000), segment 1 = cnt_drug (50000)
#define NB0 79     // ceil(20000/256)
#define NBT 275    // NB0 + ceil(50000/256)

typedef __bf16 bf16x8 __attribute__((ext_vector_type(8)));
typedef __bf16 bf16x4 __attribute__((ext_vector_type(4)));
typedef __bf16 bf16x2 __attribute__((ext_vector_type(2)));
typedef float  f32x4  __attribute__((ext_vector_type(4)));
typedef float  f32x2  __attribute__((ext_vector_type(2)));

__device__ __forceinline__ bf16x8 bz8() {
  bf16x8 v;
  #pragma unroll
  for (int j = 0; j < 8; ++j) v[j] = (__bf16)0.f;
  return v;
}

// Fast gelu: erf via Abramowitz-Stegun 7.1.27 (|erf err| <= 5e-4), 1/sqrt(2)
// folded into coefficients. gelu(x)=0.5*x*(2-p^-4) for x>=0, 0.5*x*p^-4 else.
__device__ __forceinline__ float gelu_fast(float x) {
  float ax = fabsf(x);
  float t = fmaf(ax, 0.019527f, 3.43654e-4f);
  t = fmaf(ax, t, 0.1151945f);
  t = fmaf(ax, t, 0.1968564f);
  float p = fmaf(ax, t, 1.0f);
  float p2 = p * p;
  float p4 = p2 * p2;
  float r = __builtin_amdgcn_rcpf(p4);
  float sel = (x >= 0.f) ? (2.0f - r) : r;
  return 0.5f * x * sel;
}

__device__ __forceinline__ float sigmoid_fast(float v) {
  return __builtin_amdgcn_rcpf(1.0f + __expf(-v));
}

// DPP row-rotate (within the 16-lane row): VALU-pipe lane exchange, no LDS.
// ctrl 0x120|N = ROW_ROR:N. Four levels (1,2,4,8) = rotation all-reduce.
template <int N>
__device__ __forceinline__ float dpp_ror(float v) {
  int r = __builtin_amdgcn_update_dpp(0, __builtin_bit_cast(int, v),
                                      0x120 | N, 0xF, 0xF, false);
  return __builtin_bit_cast(float, r);
}

// ---------------------------------------------------------------------------
// Persistent multi-segment [M,128] @ [128,128] GEMM.
// Per-segment block partition (bstart[5]); each block stages its segment's W
// to LDS ONCE, then grid-strides tiles. A-fragments load directly from global
// into registers, software-pipelined one tile ahead (no barriers in the loop).
// ---------------------------------------------------------------------------
struct Seg {
  const void* A[4];
  const float* W[4];
  const float* bias[4];
  void* out[4];
  int M[4];
  int bstart[5];
};

template <int AIN_BF16, int OUT_BF16>
__global__ __launch_bounds__(256)
void gemm_seg(Seg d)
{
  __shared__ __bf16 Wt[128][136];   // W transposed: Wt[n][k]

  const int b = blockIdx.x;
  const int sidx = (b >= d.bstart[3]) ? 3 : (b >= d.bstart[2]) ? 2
                 : (b >= d.bstart[1]) ? 1 : 0;
  const int nb = d.bstart[sidx + 1] - d.bstart[sidx];
  const int lb = b - d.bstart[sidx];
  const float* W = d.W[sidx];
  const float* bias = d.bias[sidx];
  const int M = d.M[sidx];
  const int ntiles = (M + 63) >> 6;
  const int tid = threadIdx.x;
  const int wv = tid >> 6, lane = tid & 63;
  const int m16 = lane & 15, quad = lane >> 4;

  for (int idx = tid; idx < 16384; idx += 256) {
    int k = idx >> 7, n = idx & 127;
    Wt[n][k] = (__bf16)W[idx];
  }
  __syncthreads();   // the only barrier: Wt visible to all waves

  float bv[8];
  #pragma unroll
  for (int ct = 0; ct < 8; ++ct) bv[ct] = bias[ct * 16 + m16];

  auto load_afr = [&](int t, bf16x8* afr) {
    const int arow = (t << 6) + wv * 16 + m16;
    const bool ok = (t < ntiles) && (arow < M);
    if (AIN_BF16) {
      const __bf16* ap = (const __bf16*)d.A[sidx] + (long)arow * 128 + quad * 8;
      #pragma unroll
      for (int kt = 0; kt < 4; ++kt)
        afr[kt] = ok ? *(const bf16x8*)(ap + kt * 32) : bz8();
    } else {
      const float* ap = (const float*)d.A[sidx] + (long)arow * 128 + quad * 8;
      #pragma unroll
      for (int kt = 0; kt < 4; ++kt) {
        bf16x8 v = bz8();
        if (ok) {
          f32x4 lo = *(const f32x4*)(ap + kt * 32);
          f32x4 hi = *(const f32x4*)(ap + kt * 32 + 4);
          #pragma unroll
          for (int j = 0; j < 4; ++j) { v[j] = (__bf16)lo[j]; v[4 + j] = (__bf16)hi[j]; }
        }
        afr[kt] = v;
      }
    }
  };

  bf16x8 afr[4];
  if (lb < ntiles) load_afr(lb, afr);

  for (int t = lb; t < ntiles; t += nb) {
    bf16x8 nafr[4];
    load_afr(t + nb, nafr);   // in flight during this tile's MFMA + stores

    f32x4 acc[8];
    #pragma unroll
    for (int ct = 0; ct < 8; ++ct) acc[ct] = (f32x4){0.f, 0.f, 0.f, 0.f};
    #pragma unroll
    for (int kt = 0; kt < 4; ++kt) {
      #pragma unroll
      for (int ct = 0; ct < 8; ++ct) {
        bf16x8 bfr = *(const bf16x8*)&Wt[ct * 16 + m16][kt * 32 + quad * 8];
        acc[ct] = __builtin_amdgcn_mfma_f32_16x16x32_bf16(afr[kt], bfr, acc[ct], 0, 0, 0);
      }
    }

    // C/D layout: col=lane&15, row=quad*4+reg
    const int rb = (t << 6) + wv * 16 + quad * 4;
    #pragma unroll
    for (int ct = 0; ct < 8; ++ct) {
      const int col = ct * 16 + m16;
      #pragma unroll
      for (int rg = 0; rg < 4; ++rg) {
        int gr = rb + rg;
        if (gr < M) {
          float v = acc[ct][rg] + bv[ct];
          if (OUT_BF16) ((__bf16*)d.out[sidx])[(long)gr * 128 + col] = (__bf16)v;
          else          ((float*)d.out[sidx])[(long)gr * 128 + col] = v;
        }
      }
    }
    #pragma unroll
    for (int kt = 0; kt < 4; ++kt) afr[kt] = nafr[kt];
  }
}

// ---------------------------------------------------------------------------
// Edge gate, SORTED ORDER: row p of `out` is the gate of edge sorted_t[p],
// so the aggregate reads it fully sequentially. 768 blocks (3 blocks/CU,
// 12 waves/CU). Sigmoid phase stores DIRECT C-layout to global; gelu LDS
// trip stays (needed for layer-2 A-frag relayout).
// R10: pad 136 -> 132 (264 B rows = 66 dwords, 66%32=2): the C-layout bf16
// H-writes go from 4-way to 2-way bank aliasing (2-way is free, m136);
// quads land in disjoint 8-bank groups. LDS 50.7 KB, still 3 blocks/CU.
// ---------------------------------------------------------------------------
__global__ __launch_bounds__(256)
void gate_kernel(const float* __restrict__ EA, const float* __restrict__ W2,
                 const float* __restrict__ Wg1, const float* __restrict__ bg1,
                 const float* __restrict__ bg2, const int* __restrict__ sorted_t,
                 __bf16* __restrict__ out)
{
  __shared__ __bf16 Wt[128][132];
  __shared__ __bf16 H[64][132];
  const int tid = threadIdx.x;
  const int wv = tid >> 6, lane = tid & 63;
  const int m16 = lane & 15, quad = lane >> 4;

  for (int idx = tid; idx < 16384; idx += 256) {
    int k = idx >> 7, n = idx & 127;
    Wt[n][k] = (__bf16)W2[idx];
  }
  __syncthreads();

  // layer-1 B-fragments: B[n=ct*16+m16][k=quad*8+j] = Wg1[k][n], k<8 real
  bf16x8 b1[8];
  #pragma unroll
  for (int ct = 0; ct < 8; ++ct) {
    bf16x8 v = bz8();
    if (quad == 0) {
      #pragma unroll
      for (int j = 0; j < 8; ++j) v[j] = (__bf16)Wg1[j * 128 + ct * 16 + m16];
    }
    b1[ct] = v;
  }
  float b1v[8], b2v[8];
  #pragma unroll
  for (int ct = 0; ct < 8; ++ct) {
    b1v[ct] = bg1[ct * 16 + m16];
    b2v[ct] = bg2[ct * 16 + m16];
  }

  const int ntiles = (NE + 63) >> 6;   // 3907
  const int hr = wv * 16 + quad * 4;   // C-layout row base in H stripe
  const int ar = wv * 16 + m16;        // A-frag / row-major row in H stripe

  for (int t = blockIdx.x; t < ntiles; t += gridDim.x) {
    const int p = (t << 6) + wv * 16 + m16;   // sorted position == out row

    // layer-1 A-frag: quad 0 holds the gathered ea row (k=0..7), rest zero
    bf16x8 a1 = bz8();
    if (quad == 0 && p < NE) {
      int e = sorted_t[p];
      f32x4 e0 = *(const f32x4*)(EA + (long)e * 8);
      f32x4 e1 = *(const f32x4*)(EA + (long)e * 8 + 4);
      #pragma unroll
      for (int j = 0; j < 4; ++j) { a1[j] = (__bf16)e0[j]; a1[4 + j] = (__bf16)e1[j]; }
    }
    f32x4 h[8];
    #pragma unroll
    for (int ct = 0; ct < 8; ++ct)
      h[ct] = __builtin_amdgcn_mfma_f32_16x16x32_bf16(a1, b1[ct], (f32x4){0.f,0.f,0.f,0.f}, 0, 0, 0);

    // bias + gelu in C-layout -> wave-private H stripe (in-order DS pipe)
    #pragma unroll
    for (int ct = 0; ct < 8; ++ct) {
      const int col = ct * 16 + m16;
      #pragma unroll
      for (int rg = 0; rg < 4; ++rg)
        H[hr + rg][col] = (__bf16)gelu_fast(h[ct][rg] + b1v[ct]);
    }
    asm volatile("s_waitcnt lgkmcnt(0)" ::: "memory");

    bf16x8 afr[4];
    #pragma unroll
    for (int kt = 0; kt < 4; ++kt)
      afr[kt] = *(const bf16x8*)&H[ar][kt * 32 + quad * 8];
    asm volatile("" ::: "memory");

    f32x4 acc[8];
    #pragma unroll
    for (int ct = 0; ct < 8; ++ct) acc[ct] = (f32x4){0.f, 0.f, 0.f, 0.f};
    #pragma unroll
    for (int kt = 0; kt < 4; ++kt) {
      #pragma unroll
      for (int ct = 0; ct < 8; ++ct) {
        bf16x8 bfr = *(const bf16x8*)&Wt[ct * 16 + m16][kt * 32 + quad * 8];
        acc[ct] = __builtin_amdgcn_mfma_f32_16x16x32_bf16(afr[kt], bfr, acc[ct], 0, 0, 0);
      }
    }

    // sigmoid: DIRECT C-layout global stores (no second LDS trip).
    // Per instr: m16 spans 16 contiguous cols (32 B), quad spans 4 rows.
    const long rowbase = (long)(t << 6) + hr;
    #pragma unroll
    for (int ct = 0; ct < 8; ++ct) {
      const int col = ct * 16 + m16;
      #pragma unroll
      for (int rg = 0; rg < 4; ++rg)
        out[(rowbase + rg) * 128 + col] = (__bf16)sigmoid_fast(acc[ct][rg] + b2v[ct]);
    }
  }
}

// ---------------------------------------------------------------------------
// Counting sort of edges by destination node (both edge types per launch).
// scatter2 also materializes ssrc[p] = si[sorted[p]] (drops a dependency
// level in the aggregate).
// ---------------------------------------------------------------------------
__global__ __launch_bounds__(256)
void histo2(const int* __restrict__ di_t, const int* __restrict__ di_r,
            int* __restrict__ cnt_dis, int* __restrict__ cnt_drug, int half) {
  int b = blockIdx.x;
  if (b < half) {
    int i = b * 256 + threadIdx.x;
    if (i < NE) atomicAdd(&cnt_dis[di_t[i]], 1);
  } else {
    int i = (b - half) * 256 + threadIdx.x;
    if (i < NE) atomicAdd(&cnt_drug[di_r[i]], 1);
  }
}

__global__ __launch_bounds__(256)
void scatter2(const int* __restrict__ di_t, const int* __restrict__ di_r,
              const int* __restrict__ si_t, const int* __restrict__ si_r,
              int* __restrict__ cur_dis, int* __restrict__ cur_drug,
              int* __restrict__ sorted_t, int* __restrict__ ssrc_t,
              int* __restrict__ ssrc_r, int half) {
  int b = blockIdx.x;
  if (b < half) {
    int i = b * 256 + threadIdx.x;
    if (i < NE) {
      int p = atomicAdd(&cur_dis[di_t[i]], 1);
      sorted_t[p] = i;
      ssrc_t[p] = si_t[i];
    }
  } else {
    int i = (b - half) * 256 + threadIdx.x;
    if (i < NE) {
      int p = atomicAdd(&cur_drug[di_r[i]], 1);
      ssrc_r[p] = si_r[i];
    }
  }
}

// ---------------------------------------------------------------------------
// Device-wide segmented exclusive scan over concatenated cnt_dis||cnt_drug.
// 2 kernels: block-prefix computed redundantly per block in scan_final2.
// ---------------------------------------------------------------------------
__device__ __forceinline__ void seg_geom(int b, int& base, int& n, int& lb) {
  if (b < NB0) { base = 0;     n = 20000; lb = b; }
  else         { base = 20000; n = 50000; lb = b - NB0; }
}

__global__ __launch_bounds__(256)
void scan_partial(const int* __restrict__ cnt, int* __restrict__ bsum) {
  __shared__ int sh[256];
  int b = blockIdx.x, t = threadIdx.x;
  int base, n, lb; seg_geom(b, base, n, lb);
  int i = lb * 256 + t;
  sh[t] = (i < n) ? cnt[base + i] : 0;
  __syncthreads();
  for (int d = 1; d < 256; d <<= 1) {
    int vv = (t >= d) ? sh[t - d] : 0;
    __syncthreads();
    sh[t] += vv;
    __syncthreads();
  }
  if (t == 255) bsum[b] = sh[255];
}

__global__ __launch_bounds__(256)
void scan_final2(const int* __restrict__ cnt, const int* __restrict__ bsum,
                 int* __restrict__ offs, int* __restrict__ cursor) {
  __shared__ int v[512];
  __shared__ int f[512];
  __shared__ int sh[256];
  const int b = blockIdx.x, t = threadIdx.x;

  // ---- redundant segmented block-prefix over bsum[0..NBT) (2 elems/thread)
  for (int i = t; i < 512; i += 256) {
    v[i] = (i < NBT) ? bsum[i] : 0;
    f[i] = (i == 0 || i == NB0 || i >= NBT) ? 1 : 0;
  }
  __syncthreads();
  for (int d = 1; d < 512; d <<= 1) {
    const int i0 = t, i1 = t + 256;
    int vv0 = 0, ff0 = 1, vv1 = 0, ff1 = 1;
    if (i0 >= d) { vv0 = v[i0 - d]; ff0 = f[i0 - d]; }
    if (i1 >= d) { vv1 = v[i1 - d]; ff1 = f[i1 - d]; }
    __syncthreads();
    if (i0 >= d && !f[i0]) { v[i0] += vv0; f[i0] |= ff0; }
    if (i1 >= d && !f[i1]) { v[i1] += vv1; f[i1] |= ff1; }
    __syncthreads();
  }
  // exclusive prefix for THIS block: inclusive v[b] minus own bsum[b]
  const int bexc_b = v[b] - bsum[b];

  // ---- local 256-element scan (identical to old scan_final)
  int base, n, lb; seg_geom(b, base, n, lb);
  int i = lb * 256 + t;
  int own = (i < n) ? cnt[base + i] : 0;
  sh[t] = own;
  __syncthreads();
  for (int d = 1; d < 256; d <<= 1) {
    int vv = (t >= d) ? sh[t - d] : 0;
    __syncthreads();
    sh[t] += vv;
    __syncthreads();
  }
  int off = bexc_b + sh[t] - own;
  if (i < n) { offs[base + i] = off; cursor[base + i] = off; }
}

// ---------------------------------------------------------------------------
// Merged gather-side aggregation, SCALARIZED control/address plane.
// One 64-lane wave per destination node; lane owns channels {2l, 2l+1}.
//
// R10: period-3 STATIC buffer rotation (loop unrolled 3x, buffer roles
// rotate by code position) — eliminates the 8 rotation movs AND the 8
// zero-fill movs per 4-edge batch of the previous 3-stage pipeline
// (~4 VALU/edge). A batch's buffer is only computed if its issue-guard
// (j+8<m) held 2 iterations earlier, so no zero-fill is needed; all
// indices stay compile-time constant (no scratch spill).
//  * batch-level WAVE-UNIFORM guards (m SGPR -> s_cbranch)
//  * ids 3 batches ahead (SGPRs), rows in flight for j+4 and j+8
//  * scalar clamps, DPP row_ror reduce, log2-domain exp, masked ex.
// ---------------------------------------------------------------------------
#define AGG_STEP(XC, GC, XT, GT, JJ)                                      \
  {                                                                       \
    if ((JJ) + 8 < m) {                                                   \
      _Pragma("unroll")                                                   \
      for (int u = 0; u < 4; ++u) {                                       \
        XT[u] = row_load(s2[u]);                                          \
        if (isDis) GT[u] = gate_load((JJ) + 8 + u);                       \
      }                                                                   \
    }                                                                     \
    if ((JJ) + 12 < m) {                                                  \
      _Pragma("unroll")                                                   \
      for (int u = 0; u < 4; ++u) s2[u] = sfetch((JJ) + 12 + u);          \
    }                                                                     \
    float part[4], mm0[4], mm1[4];                                        \
    _Pragma("unroll")                                                     \
    for (int u = 0; u < 4; ++u) {                                         \
      float xs0 = (float)XC[u][0], xs1 = (float)XC[u][1];                 \
      float m0 = xs0 + xd0, m1 = xs1 + xd1;                               \
      if (isDis) { m0 *= (float)GC[u][0]; m1 *= (float)GC[u][1]; }        \
      mm0[u] = m0; mm1[u] = m1;                                           \
      part[u] = xs0 * xdl0 + xs1 * xdl1 + m0 * at0 + m1 * at1;            \
    }                                                                     \
    _Pragma("unroll")                                                     \
    for (int u = 0; u < 4; ++u) part[u] += dpp_ror<1>(part[u]);           \
    _Pragma("unroll")                                                     \
    for (int u = 0; u < 4; ++u) part[u] += dpp_ror<2>(part[u]);           \
    _Pragma("unroll")                                                     \
    for (int u = 0; u < 4; ++u) part[u] += dpp_ror<4>(part[u]);           \
    _Pragma("unroll")                                                     \
    for (int u = 0; u < 4; ++u) part[u] += dpp_ror<8>(part[u]);           \
    _Pragma("unroll")                                                     \
    for (int u = 0; u < 4; ++u) {                                         \
      float ex = ((JJ) + u < m) ? __builtin_amdgcn_exp2f(part[u]) : 0.f;  \
      n0 += mm0[u] * ex;                                                  \
      n1 += mm1[u] * ex;                                                  \
      den += ex;                                                          \
    }                                                                     \
  }

__global__ __launch_bounds__(256)
void aggregate2(const __bf16* __restrict__ Xs_t, const __bf16* __restrict__ Xd_t,
                const __bf16* __restrict__ Xs_r, const __bf16* __restrict__ Xd_r,
                const int* __restrict__ ssrc_t, const int* __restrict__ ssrc_r,
                const int* __restrict__ offs, const int* __restrict__ cnt,
                const __bf16* __restrict__ gate_s,
                const float* __restrict__ attn_t, const float* __restrict__ attn_r,
                __bf16* __restrict__ aggr_dis, __bf16* __restrict__ aggr_drug)
{
  const int gw0 = (int)((blockIdx.x * 256 + threadIdx.x) >> 6);
  if (gw0 >= N_DIS + N_DRUG) return;
  const int gw = __builtin_amdgcn_readfirstlane(gw0);   // wave-uniform -> SGPR
  const int lane = threadIdx.x & 63;
  const int c = lane * 2;
  const bool isDis = gw < N_DIS;
  const int node = isDis ? gw : gw - N_DIS;
  const __bf16* __restrict__ Xs = isDis ? Xs_t : Xs_r;
  const __bf16* __restrict__ Xd = isDis ? Xd_t : Xd_r;
  const int* __restrict__ ssrc = isDis ? ssrc_t : ssrc_r;
  const float* __restrict__ attn = isDis ? attn_t : attn_r;
  __bf16* __restrict__ outp = isDis ? aggr_dis : aggr_drug;
  const int Ns = isDis ? N_DRUG : N_DIS;

  const int start = __builtin_amdgcn_readfirstlane(offs[gw]);
  const int m     = __builtin_amdgcn_readfirstlane(cnt[gw]);

  // per-lane constants; 1/sqrt(HD) and log2(e) folded into the logit terms
  const float LOG2E = 1.4426950408889634f;
  f32x2 at = *(const f32x2*)(attn + c);
  bf16x2 xdb = *(const bf16x2*)(Xd + (size_t)node * 128 + c);
  const float xd0 = (float)xdb[0], xd1 = (float)xdb[1];
  const float xdl0 = xd0 * (0.17677669529663687f * LOG2E);
  const float xdl1 = xd1 * (0.17677669529663687f * LOG2E);
  const float at0 = at[0] * LOG2E, at1 = at[1] * LOG2E;

  // scalar source-id fetch: clamped index, value forced to SGPR, clamped to
  // a valid row so the gather address is always in initialized memory.
  auto sfetch = [&](int jn) -> int {
    int idx = start + jn;
    if (idx > NE - 1) idx = NE - 1;                     // scalar clamp
    int s = __builtin_amdgcn_readfirstlane(ssrc[idx]);
    return ((unsigned)s < (unsigned)Ns) ? s : 0;        // scalar clamp
  };
  auto row_load = [&](int s) -> bf16x2 {                // SGPR base + lane voff
    return *(const bf16x2*)(Xs + (size_t)s * 128 + c);
  };
  auto gate_load = [&](int jn) -> bf16x2 {              // sequential rows
    return *(const bf16x2*)(gate_s + (size_t)(start + jn) * 128 + c);
  };

  const bf16x2 z2 = {(__bf16)0.f, (__bf16)0.f};
  bf16x2 xa[4], ga[4], xb[4], gb[4], xc[4], gc[4];
  #pragma unroll
  for (int u = 0; u < 4; ++u) {
    xa[u] = z2; ga[u] = z2; xb[u] = z2; gb[u] = z2; xc[u] = z2; gc[u] = z2;
  }

  // ids for batches 0/1/2 — independent scalar loads, one lgkm wait covers all
  int s0[4], s1[4], s2[4];
  #pragma unroll
  for (int u = 0; u < 4; ++u) s0[u] = sfetch(u);
  #pragma unroll
  for (int u = 0; u < 4; ++u) s1[u] = sfetch(4 + u);
  #pragma unroll
  for (int u = 0; u < 4; ++u) s2[u] = sfetch(8 + u);

  // rows for batch 0 (always) and batch 1 (if it exists)
  #pragma unroll
  for (int u = 0; u < 4; ++u) {
    xa[u] = row_load(s0[u]);
    if (isDis) ga[u] = gate_load(u);
  }
  if (m > 4) {
    #pragma unroll
    for (int u = 0; u < 4; ++u) {
      xb[u] = row_load(s1[u]);
      if (isDis) gb[u] = gate_load(4 + u);
    }
  }

  float n0 = 0.f, n1 = 0.f, den = 0.f;

  // period-3 static rotation: compute A|B|C while issuing rows for the
  // third buffer ahead. All guards wave-uniform; no data movement.
  int j = 0;
  while (j < m) {
    AGG_STEP(xa, ga, xc, gc, j); j += 4; if (j >= m) break;
    AGG_STEP(xb, gb, xa, ga, j); j += 4; if (j >= m) break;
    AGG_STEP(xc, gc, xb, gb, j); j += 4;
  }

  float r = __builtin_amdgcn_rcpf(den + 1e-16f);
  bf16x2 o;
  o[0] = (__bf16)(n0 * r);
  o[1] = (__bf16)(n1 * r);
  *(bf16x2*)(outp + (size_t)node * 128 + c) = o;
}

// ---------------------------------------------------------------------------
extern "C" void kernel_launch(void* const* d_in, const int* in_sizes, int n_in,
                              void* d_out, int out_size, void* d_ws, size_t ws_size,
                              hipStream_t stream)
{
  const float* x_drug  = (const float*)d_in[0];
  const float* x_dis   = (const float*)d_in[1];
  const float* ea      = (const float*)d_in[2];
  const int*   si_t    = (const int*)d_in[3];
  const int*   di_t    = (const int*)d_in[4];
  const int*   si_r    = (const int*)d_in[5];
  const int*   di_r    = (const int*)d_in[6];
  const float* Ws_t    = (const float*)d_in[7];
  const float* bs_t    = (const float*)d_in[8];
  const float* Wd_t    = (const float*)d_in[9];
  const float* bd_t    = (const float*)d_in[10];
  const float* attn_t  = (const float*)d_in[11];
  const float* Wg1     = (const float*)d_in[12];
  const float* bg1     = (const float*)d_in[13];
  const float* Wg2     = (const float*)d_in[14];
  const float* bg2     = (const float*)d_in[15];
  const float* Ws_r    = (const float*)d_in[16];
  const float* bs_r    = (const float*)d_in[17];
  const float* Wd_r    = (const float*)d_in[18];
  const float* bd_r    = (const float*)d_in[19];
  const float* attn_r  = (const float*)d_in[20];
  const float* Wo_drug = (const float*)d_in[21];
  const float* bo_drug = (const float*)d_in[22];
  const float* Wo_dis  = (const float*)d_in[23];
  const float* bo_dis  = (const float*)d_in[24];

  // workspace layout (~104 MB); X/gate tensors bf16.
  // aggr_dis aliases Xd_t, aggr_drug aliases Xd_r (row-for-row safe).
  __bf16* wsb      = (__bf16*)d_ws;
  __bf16* Xs_t     = wsb;                  // 50000*128
  __bf16* Xd_t     = Xs_t + 6400000;       // 20000*128 (-> aggr_dis)
  __bf16* Xs_r     = Xd_t + 2560000;       // 20000*128
  __bf16* Xd_r     = Xs_r + 2560000;       // 50000*128 (-> aggr_drug)
  __bf16* gate     = Xd_r + 6400000;       // NE_PAD*128, SORTED order
  int* cnt_dis    = (int*)(gate + (long)NE_PAD * 128);  // 20000  --+ contiguous:
  int* cnt_drug   = cnt_dis + 20000;       // 50000             | zeroed+scanned
  int* offs_dis   = cnt_drug + 50000;      // 20000             | as one region
  int* offs_drug  = offs_dis + 20000;      // 50000             |
  int* cur_dis    = offs_drug + 50000;     // 20000             |
  int* cur_drug   = cur_dis + 20000;       // 50000           --+
  int* sorted_t   = cur_drug + 50000;      // 250000 (gate kernel only)
  int* ssrc_t     = sorted_t + 250000;     // 250000
  int* ssrc_r     = ssrc_t + 250000;       // 250000
  int* bsum       = ssrc_r + 250000;       // 275
  int* bexc       = bsum + 512;            // 275 (unused)

  __bf16* aggr_dis  = Xd_t;
  __bf16* aggr_drug = Xd_r;

  float* out_drug = (float*)d_out;
  float* out_dis  = out_drug + (long)N_DRUG * 128;

  hipMemsetAsync(cnt_dis, 0, 70000 * sizeof(int), stream);

  const int eb = (NE + 255) / 256;         // 977

  // counting sort by destination (both convs), device-wide 2-phase scan
  // (block-prefix computed redundantly per block in scan_final2)
  histo2<<<2 * eb, 256, 0, stream>>>(di_t, di_r, cnt_dis, cnt_drug, eb);
  scan_partial<<<NBT, 256, 0, stream>>>(cnt_dis, bsum);
  scan_final2<<<NBT, 256, 0, stream>>>(cnt_dis, bsum, offs_dis, cur_dis);
  scatter2<<<2 * eb, 256, 0, stream>>>(di_t, di_r, si_t, si_r, cur_dis, cur_drug,
                                       sorted_t, ssrc_t, ssrc_r, eb);

  // 4 node transforms, persistent per-segment blocks (tiles 782/313/313/782)
  Seg nd;
  nd.A[0] = x_drug; nd.W[0] = Ws_t; nd.bias[0] = bs_t; nd.out[0] = Xs_t; nd.M[0] = N_DRUG;
  nd.A[1] = x_dis;  nd.W[1] = Wd_t; nd.bias[1] = bd_t; nd.out[1] = Xd_t; nd.M[1] = N_DIS;
  nd.A[2] = x_dis;  nd.W[2] = Ws_r; nd.bias[2] = bs_r; nd.out[2] = Xs_r; nd.M[2] = N_DIS;
  nd.A[3] = x_drug; nd.W[3] = Wd_r; nd.bias[3] = bd_r; nd.out[3] = Xd_r; nd.M[3] = N_DRUG;
  nd.bstart[0] = 0; nd.bstart[1] = 274; nd.bstart[2] = 384; nd.bstart[3] = 494; nd.bstart[4] = 768;
  gemm_seg<0, 1><<<768, 256, 0, stream>>>(nd);

  // edge gate in sorted order: 768 blocks (3 blocks/CU at 50.7 KB LDS,
  // 12 waves/CU)
  gate_kernel<<<768, 256, 0, stream>>>(ea, Wg2, Wg1, bg1, bg2, sorted_t, gate);

  // merged gather-side aggregation: 70000 waves, one per destination node
  aggregate2<<<(N_DIS + N_DRUG + 3) / 4, 256, 0, stream>>>(
      Xs_t, Xd_t, Xs_r, Xd_r, ssrc_t, ssrc_r, offs_dis, cnt_dis,
      gate, attn_t, attn_r, aggr_dis, aggr_drug);

  // 2 output linears, persistent per-segment blocks (tiles 782/313)
  Seg od;
  od.A[0] = aggr_drug; od.W[0] = Wo_drug; od.bias[0] = bo_drug; od.out[0] = out_drug; od.M[0] = N_DRUG;
  od.A[1] = aggr_dis;  od.W[1] = Wo_dis;  od.bias[1] = bo_dis;  od.out[1] = out_dis;  od.M[1] = N_DIS;
  od.A[2] = od.A[1];   od.W[2] = od.W[1]; od.bias[2] = od.bias[1]; od.out[2] = od.out[1]; od.M[2] = N_DIS;
  od.A[3] = od.A[1];   od.W[3] = od.W[1]; od.bias[3] = od.bias[1]; od.out[3] = od.out[1]; od.M[3] = N_DIS;
  od.bstart[0] = 0; od.bstart[1] = 548; od.bstart[2] = 768; od.bstart[3] = 768; od.bstart[4] = 768;
  gemm_seg<1, 0><<<768, 256, 0, stream>>>(od);
}